// Round 3
// baseline (773.470 us; speedup 1.0000x reference)
//
#include <hip/hip_runtime.h>
#include <hip/hip_bf16.h>
#include <math.h>

#define H 64
#define DM 128
#define GDIM 192      // 3*H
#define BSZ 32
#define SEQ 500
#define NROW (BSZ*SEQ)  // 16000
#define LIBN 2145
#define FFD 128
#define KPAD 2176     // 68*32 (theta K padded)
#define NKC 68        // K chunks of 32

typedef __attribute__((ext_vector_type(8))) short short8;   // bf16x8 MFMA operand
typedef __attribute__((ext_vector_type(4))) float f32x4;    // MFMA accumulator
typedef __attribute__((ext_vector_type(4))) unsigned u32x4;

__device__ __forceinline__ float sigf(float x) {
    return 1.0f / (1.0f + __expf(-x));
}
__device__ __forceinline__ float tanhfast(float x) {
    x = fminf(fmaxf(x, -15.0f), 15.0f);
    float t = __expf(-2.0f * x);
    return (1.0f - t) / (1.0f + t);
}
__device__ __forceinline__ short bf16r(float f) {   // fp32 -> bf16 rne
    unsigned u = __float_as_uint(f);
    unsigned r = (u + 0x7fffu + ((u >> 16) & 1u)) >> 16;
    return (short)r;
}

// raw barrier: LDS ordering only — prefetch loads / h1 stores stay in flight.
#define BAR_LGKM() asm volatile("s_waitcnt lgkmcnt(0)\n\ts_barrier" ::: "memory")

// async global->LDS, 16B per lane, dst = uniform base + lane*16
__device__ __forceinline__ void gload_lds16(const float* g, float* l) {
    __builtin_amdgcn_global_load_lds(
        (const __attribute__((address_space(1))) unsigned int*)g,
        (__attribute__((address_space(3))) unsigned int*)l, 16, 0, 0);
}

// ---------------- pack Wih0 (192,128) -> WTp[k4][g][e] for coalesced float4 loads ----
__global__ void pack_wih0(const float* __restrict__ w, float* __restrict__ wt) {
    int idx = blockIdx.x * 256 + threadIdx.x;
    if (idx >= GDIM * DM) return;
    int e  = idx & 3;
    int g  = (idx >> 2) % GDIM;
    int k4 = idx / (GDIM * 4);
    wt[idx] = w[g * DM + k4 * 4 + e];
}

// ---- prepack coef (2145x64, zero-pad to 2176) into bf16 B-fragment-linear order ----
__global__ void pack_coef_frag(const float* __restrict__ coef, short* __restrict__ cp) {
    int idx = blockIdx.x * 256 + threadIdx.x;           // 68*4*64*8 = 139264
    int j = idx & 7, lane = (idx >> 3) & 63, nt = (idx >> 9) & 3, kc = idx >> 11;
    int k = kc * 32 + ((lane >> 4) << 3) + j;
    int c = nt * 16 + (lane & 15);
    float v = (k < LIBN) ? coef[(size_t)k * H + c] : 0.0f;
    cp[idx] = bf16r(v);
}
// ---- W1 (128,64): B = W1^T (K=64,N=128) ----
__global__ void pack_w1_frag(const float* __restrict__ w1, short* __restrict__ wp) {
    int idx = blockIdx.x * 256 + threadIdx.x;           // 2*8*64*8 = 8192
    int j = idx & 7, lane = (idx >> 3) & 63, nt = (idx >> 9) & 7, kc = idx >> 12;
    int k = kc * 32 + ((lane >> 4) << 3) + j;
    int n = nt * 16 + (lane & 15);
    wp[idx] = bf16r(w1[(size_t)n * H + k]);
}
// ---- W2 (64,128): B = W2^T (K=128,N=64) ----
__global__ void pack_w2_frag(const float* __restrict__ w2, short* __restrict__ wp) {
    int idx = blockIdx.x * 256 + threadIdx.x;           // 4*4*64*8 = 8192
    int j = idx & 7, lane = (idx >> 3) & 63, nt = (idx >> 9) & 3, kc = idx >> 11;
    int k = kc * 32 + ((lane >> 4) << 3) + j;
    int n = nt * 16 + (lane & 15);
    wp[idx] = bf16r(w2[(size_t)n * FFD + k]);
}

// ---------------- xp0 = x @ Wih0^T + bih0, stored in GRU chunk layout ----------------
__global__ __launch_bounds__(192, 2) void xp0_gemm(const float* __restrict__ x,
                                                   const float* __restrict__ wtp,
                                                   const float* __restrict__ bih0,
                                                   float* __restrict__ xpT) {
    __shared__ float xs[64][DM];
    int rb = blockIdx.x * 64;
    for (int idx = threadIdx.x; idx < 64 * 32; idx += 192) {
        int r = idx >> 5, k4 = idx & 31;
        ((f32x4*)xs[r])[k4] = ((const f32x4*)(x + (size_t)(rb + r) * DM))[k4];
    }
    __syncthreads();
    int g = threadIdx.x;
    float bias = bih0[g];
    float acc[64];
#pragma unroll
    for (int r = 0; r < 64; r++) acc[r] = bias;
    for (int k4 = 0; k4 < 32; k4++) {
        f32x4 w4 = ((const f32x4*)wtp)[k4 * GDIM + g];
#pragma unroll
        for (int r = 0; r < 64; r++) {
            f32x4 xv = ((f32x4*)xs[r])[k4];
            acc[r] += w4[0] * xv[0] + w4[1] * xv[1] + w4[2] * xv[2] + w4[3] * xv[3];
        }
    }
    for (int r = 0; r < 64; r++) {
        int row = rb + r;
        int bb = row / 500;
        int ss = row - bb * 500;
        xpT[(((size_t)bb * 125 + (ss >> 2)) * GDIM + g) * 4 + (ss & 3)] = acc[r];
    }
}

// ---------------- fused 2-layer GRU scan: 3-wave / 1-barrier, LDS xp ring ------------
// One wave per matvec, full K=64 per wave, weights register-resident (192 VGPR):
//   wave0: Whh0@h0  -> h0[u] = GRU(h0[u-1], xp[u]) entirely in-lane
//   wave1: Wih1@h0  -> i1 = Wih1@h0[u-1] + bih1, handed to wave2 via LDS (f32x4)
//   wave2: Whh1@h1  -> h1[u-2] = GRU(h1[u-3], i1(h0[u-2])) entirely in-lane
// R2 regressed from VGPR spills (256 cap): hv[16] hoist + xc[4][3] register ring.
// Fix: (a) xp prefetch ring lives in LDS, filled via global_load_lds (0 VGPRs),
// counted vmcnt(3) at prefetch points only; (b) h loaded per-iteration in matvec.
__global__ __launch_bounds__(192, 1) void gru_fused(const float* __restrict__ xpT,
                                                    const float* __restrict__ whh0,
                                                    const float* __restrict__ bhh0,
                                                    const float* __restrict__ wih1,
                                                    const float* __restrict__ bih1,
                                                    const float* __restrict__ whh1,
                                                    const float* __restrict__ bhh1,
                                                    float* __restrict__ hbuf) {
    int b = blockIdx.x;
    int tid = threadIdx.x;
    int wv = __builtin_amdgcn_readfirstlane(tid >> 6);
    int lane = tid & 63;

    __shared__ __align__(16) float h0s[2][H];      // parity-buffered h0
    __shared__ __align__(16) float h1bc[H];        // wave2's own h1 broadcast
    __shared__ __align__(16) float p1s[2][H][4];   // wave1 -> wave2 handoff {r,z,n,_}
    __shared__ __align__(16) float xpl[4][768];    // 4-slot xp chunk ring (LDS, not VGPR)

    if (tid < H) { h0s[1][tid] = 0.0f; h1bc[tid] = 0.0f; }

    const float* W  = (wv == 0) ? whh0 : (wv == 1) ? wih1 : whh1;
    const float* Bv = (wv == 0) ? bhh0 : (wv == 1) ? bih1 : bhh1;
    f32x4 wrv[16], wzv[16], wnv[16];               // 192 VGPRs of weights
#pragma unroll
    for (int t = 0; t < 16; t++) {
        wrv[t] = ((const f32x4*)(W + (size_t)lane * H))[t];
        wzv[t] = ((const f32x4*)(W + (size_t)(H + lane) * H))[t];
        wnv[t] = ((const f32x4*)(W + (size_t)(2 * H + lane) * H))[t];
    }
    float br = Bv[lane], bz = Bv[H + lane], bn = Bv[2 * H + lane];

    float hreg0 = 0.0f, hreg1 = 0.0f;
    float hb4[4] = {0.f, 0.f, 0.f, 0.f};
    f32x4 xq[3] = {{0,0,0,0},{0,0,0,0},{0,0,0,0}};
    const float* xpB = xpT + (size_t)b * 125 * GDIM * 4;

    // prefetch chunk c into LDS ring slot c&3: 3 x 16B-per-lane async copies
    auto prefetch = [&](int c) {
        if (c < 125) {
            int slot = c & 3;
#pragma unroll
            for (int g3 = 0; g3 < 3; g3++)
                gload_lds16(xpB + ((size_t)c * GDIM + g3 * 64 + lane) * 4,
                            &xpl[slot][g3 * 256]);
        }
    };

    if (wv == 0) { prefetch(0); prefetch(1); }
    __syncthreads();

    // full-K matvec: per-iter wave-uniform b128 LDS read (broadcast) + 12 FMAs;
    // h4 loaded inside the loop so only ~2 live at once (R2's hv[16] hoist spilled).
    auto matvec = [&](const float* hb, float& gr, float& gz, float& gn) {
        float ar = br, az = bz, an = bn;
#pragma unroll
        for (int t = 0; t < 16; t++) {
            f32x4 h4 = ((const f32x4*)hb)[t];
            ar += wrv[t][0] * h4[0] + wrv[t][1] * h4[1]
                + wrv[t][2] * h4[2] + wrv[t][3] * h4[3];
            az += wzv[t][0] * h4[0] + wzv[t][1] * h4[1]
                + wzv[t][2] * h4[2] + wzv[t][3] * h4[3];
            an += wnv[t][0] * h4[0] + wnv[t][1] * h4[1]
                + wnv[t][2] * h4[2] + wnv[t][3] * h4[3];
        }
        gr = ar; gz = az; gn = an;
    };

    // e = u&3 (compile-time at each call site); parities fold to constants.
    auto step = [&](int u, int e) {
        BAR_LGKM();   // one barrier per step: makes prior step's h0/p1 writes visible
        if (wv == 0) {
            if (u < SEQ) {
                float gr, gz, gn;
                matvec(h0s[(e + 1) & 1], gr, gz, gn);          // h0[u-1]
                float rg = sigf(xq[0][e] + gr);
                float zg = sigf(xq[1][e] + gz);
                float ng = tanhfast(xq[2][e] + rg * gn);
                hreg0 = (1.0f - zg) * ng + zg * hreg0;
                h0s[e & 1][lane] = hreg0;                      // h0[u]
            }
        } else if (wv == 1) {
            if (u >= 1 && u <= 500) {
                float ar, az, an;
                matvec(h0s[(e + 1) & 1], ar, az, an);          // Wih1 @ h0[u-1] + bih1
                *(f32x4*)&p1s[(e + 1) & 1][lane][0] = (f32x4){ar, az, an, 0.0f};
            }
        } else {
            if (u >= 2) {
                float gr, gz, gn;
                matvec(h1bc, gr, gz, gn);                      // Whh1 @ h1[u-3] + bhh1
                f32x4 pv = *(const f32x4*)&p1s[e & 1][lane][0];// i1(h0[u-2])
                float rg = sigf(pv[0] + gr);
                float zg = sigf(pv[1] + gz);
                float ng = tanhfast(pv[2] + rg * gn);
                hreg1 = (1.0f - zg) * ng + zg * hreg1;         // h1[u-2]
                h1bc[lane] = hreg1;
                hb4[(e + 2) & 3] = hreg1;                      // t=u-2, t&3=(e+2)&3
                if (e == 1) {                                  // t&3==3: flush h1[u-5..u-2]
                    float* dst = hbuf + ((size_t)b * SEQ + (u - 5)) * H + lane;
#pragma unroll
                    for (int t = 0; t < 4; t++) dst[t * H] = hb4[t];
                }
            }
        }
    };

    // per 4-step group: wave0 (maybe) prefetches 2 chunks ahead, then pulls its
    // lane's 3 f32x4 for chunk sc from the LDS ring (conflict-free b128, 16B stride).
    auto loadxq = [&](int sc) {
        int slot = sc & 3;
        xq[0] = *(const f32x4*)&xpl[slot][0 * 256 + lane * 4];
        xq[1] = *(const f32x4*)&xpl[slot][1 * 256 + lane * 4];
        xq[2] = *(const f32x4*)&xpl[slot][2 * 256 + lane * 4];
    };

    for (int scb = 0; scb < 31; scb++) {
#pragma unroll
        for (int sci = 0; sci < 4; sci++) {
            int sc = scb * 4 + sci;
            if (wv == 0) {
                if ((sci & 1) == 0) {
                    prefetch(sc + 2);
                    prefetch(sc + 3);
                    // allow only the newest chunk's 3 loads outstanding -> chunks
                    // <= sc+1 are resident before this group and the next read them
                    asm volatile("s_waitcnt vmcnt(3)" ::: "memory");
                }
                loadxq(sc);
            }
            int s0 = sc * 4;
            step(s0 + 0, 0);
            step(s0 + 1, 1);
            step(s0 + 2, 2);
            step(s0 + 3, 3);
        }
    }
    if (wv == 0) {      // chunk 124 (slot 0, issued at scb=30/sci=2): drain fully
        asm volatile("s_waitcnt vmcnt(0)" ::: "memory");
        loadxq(124);
    }
    step(496, 0);
    step(497, 1);
    step(498, 2);
    step(499, 3);
    // tail u = 500, 501: drain the skewed pipeline (wave1 at 500, wave2 at 500/501)
    step(500, 0);
    step(501, 1);
}

// ---------------- MFMA SINDy layer (unchanged) ---------------------------------------
__global__ __launch_bounds__(512) void sindy_mfma(float* __restrict__ hbuf,
                                                  const short* __restrict__ cpk,
                                                  const short* __restrict__ w1p,
                                                  const short* __restrict__ w2p,
                                                  const float* __restrict__ g1,
                                                  const float* __restrict__ b1n,
                                                  const float* __restrict__ bf1,
                                                  const float* __restrict__ bf2v,
                                                  const float* __restrict__ g2,
                                                  const float* __restrict__ b2n,
                                                  float* __restrict__ out,
                                                  int final_layer) {
    __shared__ float z[64 * 68];
    __shared__ float upd[64 * 68];
    __shared__ float ff[64 * 132];
    __shared__ unsigned kmap[KPAD];
    __shared__ float bfs1[FFD], bfs2[H], g1s[H], b1s[H], g2s[H], b2s[H];

    int tid = threadIdx.x;
    int wv = __builtin_amdgcn_readfirstlane(tid >> 6);
    int lane = tid & 63;
    int row0 = blockIdx.x * 64;

    for (int idx = tid; idx < 64 * 16; idx += 512) {
        int r = idx >> 4, c4 = idx & 15;
        *(f32x4*)&z[r * 68 + c4 * 4] = *(const f32x4*)&hbuf[(size_t)(row0 + r) * H + c4 * 4];
    }
    for (int idx = tid; idx < 64 * 17; idx += 512)
        *(f32x4*)&upd[idx * 4] = (f32x4){0.f, 0.f, 0.f, 0.f};
    if (tid < 64) {
        z[tid * 68 + 64] = 1.0f; z[tid * 68 + 65] = 0.0f;
        z[tid * 68 + 66] = 0.0f; z[tid * 68 + 67] = 0.0f;
    }
    for (int k = tid; k < KPAD; k += 512) {
        unsigned a, b;
        if (k == 0) { a = 64; b = 64; }
        else if (k < 1 + H) { a = (unsigned)(k - 1); b = 64; }
        else if (k < LIBN) {
            int qq = k - (1 + H);
            double s = sqrt(16641.0 - 8.0 * (double)qq);
            int i = (int)((129.0 - s) * 0.5);
            int base = 64 * i - (i * (i - 1)) / 2;
            a = (unsigned)i; b = (unsigned)(i + (qq - base));
        } else { a = 65; b = 65; }
        kmap[k] = (a << 16) | b;
    }
    if (tid < FFD) bfs1[tid] = bf1[tid];
    if (tid < H) {
        bfs2[tid] = bf2v[tid];
        g1s[tid] = g1[tid]; b1s[tid] = b1n[tid];
        g2s[tid] = g2[tid]; b2s[tid] = b2n[tid];
    }
    __syncthreads();

    int kj0 = ((lane >> 4) << 3);
    int m0 = (wv & 3) * 16;
    int m = m0 + (lane & 15);
    int rbase = m0 + ((lane >> 4) << 2);
    int cb16 = lane & 15;
    const float* zrow = &z[m * 68];

    // ---- phase 1: upd = theta @ coef (k-split 2-way) ----
    {
        int p = wv >> 2;
        f32x4 acc[4] = {{0,0,0,0},{0,0,0,0},{0,0,0,0},{0,0,0,0}};
        for (int kc = p; kc < NKC; kc += 2) {
            int kbase = kc * 32 + kj0;
            u32x4 km0 = *(const u32x4*)&kmap[kbase];
            u32x4 km1 = *(const u32x4*)&kmap[kbase + 4];
            short8 af;
            af[0] = bf16r(zrow[km0[0] >> 16] * zrow[km0[0] & 0xffff]);
            af[1] = bf16r(zrow[km0[1] >> 16] * zrow[km0[1] & 0xffff]);
            af[2] = bf16r(zrow[km0[2] >> 16] * zrow[km0[2] & 0xffff]);
            af[3] = bf16r(zrow[km0[3] >> 16] * zrow[km0[3] & 0xffff]);
            af[4] = bf16r(zrow[km1[0] >> 16] * zrow[km1[0] & 0xffff]);
            af[5] = bf16r(zrow[km1[1] >> 16] * zrow[km1[1] & 0xffff]);
            af[6] = bf16r(zrow[km1[2] >> 16] * zrow[km1[2] & 0xffff]);
            af[7] = bf16r(zrow[km1[3] >> 16] * zrow[km1[3] & 0xffff]);
            const short* cb = cpk + ((size_t)(kc * 4) * 64 + lane) * 8;
#pragma unroll
            for (int nt = 0; nt < 4; nt++) {
                short8 bf = *(const short8*)(cb + (size_t)nt * 512);
                acc[nt] = __builtin_amdgcn_mfma_f32_16x16x32_bf16(af, bf, acc[nt], 0, 0, 0);
            }
        }
#pragma unroll
        for (int nt = 0; nt < 4; nt++)
#pragma unroll
            for (int r = 0; r < 4; r++)
                atomicAdd(&upd[(rbase + r) * 68 + nt * 16 + cb16], acc[nt][r]);
    }
    __syncthreads();

    // ---- phase 2: LN1 (wave 0) -> z ----
    if (wv == 0) {
        float v[64];
        float s1 = 0.0f;
#pragma unroll
        for (int c = 0; c < 64; c++) { v[c] = z[lane * 68 + c] + upd[lane * 68 + c]; s1 += v[c]; }
        float mn = s1 * (1.0f / 64.0f);
        float s2 = 0.0f;
#pragma unroll
        for (int c = 0; c < 64; c++) { float d = v[c] - mn; s2 += d * d; }
        float rstd = 1.0f / sqrtf(s2 * (1.0f / 64.0f) + 1e-5f);
#pragma unroll
        for (int c = 0; c < 64; c++)
            z[lane * 68 + c] = (v[c] - mn) * rstd * g1s[c] + b1s[c];
    }
    __syncthreads();

    // ---- phase 3: ff = gelu(LN1 @ W1^T + b1) ----
    {
        int nq = wv >> 2;
        f32x4 acc[4] = {{0,0,0,0},{0,0,0,0},{0,0,0,0},{0,0,0,0}};
#pragma unroll
        for (int kc = 0; kc < 2; kc++) {
            f32x4 za = *(const f32x4*)&z[m * 68 + kc * 32 + kj0];
            f32x4 zb = *(const f32x4*)&z[m * 68 + kc * 32 + kj0 + 4];
            short8 af;
            af[0] = bf16r(za[0]); af[1] = bf16r(za[1]); af[2] = bf16r(za[2]); af[3] = bf16r(za[3]);
            af[4] = bf16r(zb[0]); af[5] = bf16r(zb[1]); af[6] = bf16r(zb[2]); af[7] = bf16r(zb[3]);
#pragma unroll
            for (int t = 0; t < 4; t++) {
                int nt = nq * 4 + t;
                short8 bf = *(const short8*)(w1p + ((size_t)(kc * 8 + nt) * 64 + lane) * 8);
                acc[t] = __builtin_amdgcn_mfma_f32_16x16x32_bf16(af, bf, acc[t], 0, 0, 0);
            }
        }
#pragma unroll
        for (int t = 0; t < 4; t++) {
            int col = (nq * 4 + t) * 16 + cb16;
#pragma unroll
            for (int r = 0; r < 4; r++) {
                float v = acc[t][r] + bfs1[col];
                ff[(rbase + r) * 132 + col] = 0.5f * v * (1.0f + erff(v * 0.70710678118654752f));
            }
        }
    }
    __syncthreads();

    // ---- phase 5: upd = ff @ W2^T + b2 ----
    {
        int nh = wv >> 2;
        f32x4 acc[2] = {{0,0,0,0},{0,0,0,0}};
        const float* frow = &ff[m * 132];
#pragma unroll
        for (int kc = 0; kc < 4; kc++) {
            f32x4 fa = *(const f32x4*)&frow[kc * 32 + kj0];
            f32x4 fb = *(const f32x4*)&frow[kc * 32 + kj0 + 4];
            short8 af;
            af[0] = bf16r(fa[0]); af[1] = bf16r(fa[1]); af[2] = bf16r(fa[2]); af[3] = bf16r(fa[3]);
            af[4] = bf16r(fb[0]); af[5] = bf16r(fb[1]); af[6] = bf16r(fb[2]); af[7] = bf16r(fb[3]);
#pragma unroll
            for (int t = 0; t < 2; t++) {
                int nt = nh * 2 + t;
                short8 bf = *(const short8*)(w2p + ((size_t)(kc * 4 + nt) * 64 + lane) * 8);
                acc[t] = __builtin_amdgcn_mfma_f32_16x16x32_bf16(af, bf, acc[t], 0, 0, 0);
            }
        }
#pragma unroll
        for (int t = 0; t < 2; t++) {
            int col = (nh * 2 + t) * 16 + cb16;
#pragma unroll
            for (int r = 0; r < 4; r++)
                upd[(rbase + r) * 68 + col] = acc[t][r] + bfs2[col];
        }
    }
    __syncthreads();

    // ---- phase 6: LN2 + write (wave 0) ----
    if (wv == 0) {
        float v[64];
        float s1 = 0.0f;
#pragma unroll
        for (int c = 0; c < 64; c++) { v[c] = z[lane * 68 + c] + upd[lane * 68 + c]; s1 += v[c]; }
        float mn = s1 * (1.0f / 64.0f);
        float s2 = 0.0f;
#pragma unroll
        for (int c = 0; c < 64; c++) { float d = v[c] - mn; s2 += d * d; }
        float rstd = 1.0f / sqrtf(s2 * (1.0f / 64.0f) + 1e-5f);
        int row = row0 + lane;
#pragma unroll
        for (int c = 0; c < 64; c++) {
            float res = (v[c] - mn) * rstd * g2s[c] + b2s[c];
            if (!final_layer) {
                hbuf[(size_t)row * H + c] = res;
            } else {
                out[(size_t)row * H + c] = res;
                if (row % SEQ == SEQ - 1)
                    out[(size_t)NROW * H + (row / SEQ) * H + c] = res;
            }
        }
    }
}

extern "C" void kernel_launch(void* const* d_in, const int* in_sizes, int n_in,
                              void* d_out, int out_size, void* d_ws, size_t ws_size,
                              hipStream_t stream) {
    const float* x    = (const float*)d_in[0];
    const float* wih0 = (const float*)d_in[1];
    const float* whh0 = (const float*)d_in[2];
    const float* bih0 = (const float*)d_in[3];
    const float* bhh0 = (const float*)d_in[4];
    const float* wih1 = (const float*)d_in[5];
    const float* whh1 = (const float*)d_in[6];
    const float* bih1 = (const float*)d_in[7];
    const float* bhh1 = (const float*)d_in[8];
    const float* coeffs = (const float*)d_in[9];
    const float* ln1g = (const float*)d_in[10];
    const float* ln1b = (const float*)d_in[11];
    const float* w1   = (const float*)d_in[12];
    const float* b1   = (const float*)d_in[13];
    const float* w2   = (const float*)d_in[14];
    const float* b2   = (const float*)d_in[15];
    const float* ln2g = (const float*)d_in[16];
    const float* ln2b = (const float*)d_in[17];

    float* out = (float*)d_out;
    float* ws  = (float*)d_ws;
    float* xpT = ws;                               // 16000*192 = 3,072,000 floats
    float* wtp = ws + (size_t)NROW * GDIM;         // 24,576 floats
    short* bfa = (short*)(wtp + GDIM * DM);        // bf16 fragment area
    short* cpk[2] = { bfa, bfa + 139264 };
    short* w1pk[2] = { bfa + 2 * 139264, bfa + 2 * 139264 + 8192 };
    short* w2pk[2] = { bfa + 2 * 139264 + 2 * 8192, bfa + 2 * 139264 + 3 * 8192 };
    float* hbuf = out;                             // reuse first 1,024,000 floats of d_out

    pack_wih0<<<(GDIM * DM + 255) / 256, 256, 0, stream>>>(wih0, wtp);
    for (int l = 0; l < 2; l++) {
        pack_coef_frag<<<139264 / 256, 256, 0, stream>>>(coeffs + (size_t)l * LIBN * H, cpk[l]);
        pack_w1_frag<<<8192 / 256, 256, 0, stream>>>(w1 + (size_t)l * FFD * H, w1pk[l]);
        pack_w2_frag<<<8192 / 256, 256, 0, stream>>>(w2 + (size_t)l * H * FFD, w2pk[l]);
    }
    xp0_gemm<<<NROW / 64, 192, 0, stream>>>(x, wtp, bih0, xpT);
    gru_fused<<<BSZ, 192, 0, stream>>>(xpT, whh0, bhh0, wih1, bih1, whh1, bhh1, hbuf);
    for (int l = 0; l < 2; l++) {
        sindy_mfma<<<NROW / 64, 512, 0, stream>>>(
            hbuf, cpk[l], w1pk[l], w2pk[l],
            ln1g + l * H, ln1b + l * H, b1 + l * FFD,
            b2 + l * H, ln2g + l * H, ln2b + l * H,
            out, l == 1);
    }
}

// Round 4
// 748.274 us; speedup vs baseline: 1.0337x; 1.0337x over previous
//
#include <hip/hip_runtime.h>
#include <hip/hip_bf16.h>
#include <math.h>

#define H 64
#define DM 128
#define GDIM 192      // 3*H
#define BSZ 32
#define SEQ 500
#define NROW (BSZ*SEQ)  // 16000
#define LIBN 2145
#define FFD 128
#define KPAD 2176     // 68*32 (theta K padded)
#define NKC 68        // K chunks of 32

typedef __attribute__((ext_vector_type(8))) short short8;   // bf16x8 MFMA operand
typedef __attribute__((ext_vector_type(4))) float f32x4;    // MFMA accumulator
typedef __attribute__((ext_vector_type(4))) unsigned u32x4;

__device__ __forceinline__ float sigf(float x) {
    return 1.0f / (1.0f + __expf(-x));
}
__device__ __forceinline__ float tanhfast(float x) {
    x = fminf(fmaxf(x, -15.0f), 15.0f);
    float t = __expf(-2.0f * x);
    return (1.0f - t) / (1.0f + t);
}
__device__ __forceinline__ short bf16r(float f) {   // fp32 -> bf16 rne
    unsigned u = __float_as_uint(f);
    unsigned r = (u + 0x7fffu + ((u >> 16) & 1u)) >> 16;
    return (short)r;
}

// raw barrier: LDS ordering only — xp prefetch loads / h1 stores stay in flight
// (all cross-wave data is LDS; global loads are consumed via compiler vmcnt waits).
#define BAR_LGKM() asm volatile("s_waitcnt lgkmcnt(0)\n\ts_barrier" ::: "memory")

// ---------------- pack Wih0 (192,128) -> WTp[k4][g][e] for coalesced float4 loads ----
__global__ void pack_wih0(const float* __restrict__ w, float* __restrict__ wt) {
    int idx = blockIdx.x * 256 + threadIdx.x;
    if (idx >= GDIM * DM) return;
    int e  = idx & 3;
    int g  = (idx >> 2) % GDIM;
    int k4 = idx / (GDIM * 4);
    wt[idx] = w[g * DM + k4 * 4 + e];
}

// ---- prepack coef (2145x64, zero-pad to 2176) into bf16 B-fragment-linear order ----
__global__ void pack_coef_frag(const float* __restrict__ coef, short* __restrict__ cp) {
    int idx = blockIdx.x * 256 + threadIdx.x;           // 68*4*64*8 = 139264
    int j = idx & 7, lane = (idx >> 3) & 63, nt = (idx >> 9) & 3, kc = idx >> 11;
    int k = kc * 32 + ((lane >> 4) << 3) + j;
    int c = nt * 16 + (lane & 15);
    float v = (k < LIBN) ? coef[(size_t)k * H + c] : 0.0f;
    cp[idx] = bf16r(v);
}
// ---- W1 (128,64): B = W1^T (K=64,N=128) ----
__global__ void pack_w1_frag(const float* __restrict__ w1, short* __restrict__ wp) {
    int idx = blockIdx.x * 256 + threadIdx.x;           // 2*8*64*8 = 8192
    int j = idx & 7, lane = (idx >> 3) & 63, nt = (idx >> 9) & 7, kc = idx >> 12;
    int k = kc * 32 + ((lane >> 4) << 3) + j;
    int n = nt * 16 + (lane & 15);
    wp[idx] = bf16r(w1[(size_t)n * H + k]);
}
// ---- W2 (64,128): B = W2^T (K=128,N=64) ----
__global__ void pack_w2_frag(const float* __restrict__ w2, short* __restrict__ wp) {
    int idx = blockIdx.x * 256 + threadIdx.x;           // 4*4*64*8 = 8192
    int j = idx & 7, lane = (idx >> 3) & 63, nt = (idx >> 9) & 3, kc = idx >> 11;
    int k = kc * 32 + ((lane >> 4) << 3) + j;
    int n = nt * 16 + (lane & 15);
    wp[idx] = bf16r(w2[(size_t)n * FFD + k]);
}

// ---------------- xp0 = x @ Wih0^T + bih0, stored in GRU chunk layout ----------------
__global__ __launch_bounds__(192, 2) void xp0_gemm(const float* __restrict__ x,
                                                   const float* __restrict__ wtp,
                                                   const float* __restrict__ bih0,
                                                   float* __restrict__ xpT) {
    __shared__ float xs[64][DM];
    int rb = blockIdx.x * 64;
    for (int idx = threadIdx.x; idx < 64 * 32; idx += 192) {
        int r = idx >> 5, k4 = idx & 31;
        ((f32x4*)xs[r])[k4] = ((const f32x4*)(x + (size_t)(rb + r) * DM))[k4];
    }
    __syncthreads();
    int g = threadIdx.x;
    float bias = bih0[g];
    float acc[64];
#pragma unroll
    for (int r = 0; r < 64; r++) acc[r] = bias;
    for (int k4 = 0; k4 < 32; k4++) {
        f32x4 w4 = ((const f32x4*)wtp)[k4 * GDIM + g];
#pragma unroll
        for (int r = 0; r < 64; r++) {
            f32x4 xv = ((f32x4*)xs[r])[k4];
            acc[r] += w4[0] * xv[0] + w4[1] * xv[1] + w4[2] * xv[2] + w4[3] * xv[3];
        }
    }
    for (int r = 0; r < 64; r++) {
        int row = rb + r;
        int bb = row / 500;
        int ss = row - bb * 500;
        xpT[(((size_t)bb * 125 + (ss >> 2)) * GDIM + g) * 4 + (ss & 3)] = acc[r];
    }
}

// ---------------- fused 2-layer GRU scan: 9-wave gate-split, 64 weight VGPRs ---------
// Wave wv = m*3+g: matvec m (m0: Whh0@h0, m1: Wih1@h0, m2: Whh1@h1), gate g
// (0=r, 1=z, 2=n). Each wave owns gate-g's 64 rows with FULL K=64 -> 16 f32x4 =
// 64 weight VGPRs/lane (R2/R3's 192-reg full-K-all-gates design spilled at the 256
// cap; this is the affordable version). One row per lane: every gate value lands in
// the lane that needs it -> no cross-wave K-reduction.
//   phase 1 (9 waves): 64 FMA dot; r/z waves apply sigf, write rg/zg to LDS; m1
//     waves write raw Wih1 dots (skewed handoff to m2); n-waves keep dot in reg.
//   barrier 1 (lgkm-only)
//   phase 2 (2 n-waves): tanh chain + blend + h broadcast write (+ h1 flush).
//   barrier 2 (lgkm-only)
// Skew identical to R2 (verified): m0 at u -> h0[u]; m1 at u -> i1[u-1]; m2 at u ->
// h1[u-2]. xp prefetch ring stays in regs (4 x f32x4, compile-time indexed) and
// survives across lgkm barriers (no vmcnt drain).
__global__ __launch_bounds__(576, 2) void gru_fused(const float* __restrict__ xpT,
                                                    const float* __restrict__ whh0,
                                                    const float* __restrict__ bhh0,
                                                    const float* __restrict__ wih1,
                                                    const float* __restrict__ bih1,
                                                    const float* __restrict__ whh1,
                                                    const float* __restrict__ bhh1,
                                                    float* __restrict__ hbuf) {
    int b = blockIdx.x;
    int tid = threadIdx.x;
    int wv = __builtin_amdgcn_readfirstlane(tid >> 6);   // 0..8
    int lane = tid & 63;
    int m = wv / 3;            // 0,1,2 (wave-uniform)
    int g = wv % 3;            // 0=r, 1=z, 2=n

    __shared__ __align__(16) float h0s[2][H];      // parity-buffered h0 broadcast
    __shared__ __align__(16) float h1bc[H];        // h1 broadcast (single buffer)
    __shared__ __align__(16) float p1s[2][3][H];   // m1 -> m2 raw-dot handoff
    __shared__ __align__(16) float sg0[2][H];      // layer0 rg / zg (same-step)
    __shared__ __align__(16) float sg1[2][H];      // layer1 rg / zg (same-step)

    if (tid < H) { h0s[1][tid] = 0.0f; h1bc[tid] = 0.0f; }

    const float* W  = (m == 0) ? whh0 : (m == 1) ? wih1 : whh1;
    const float* Bv = (m == 0) ? bhh0 : (m == 1) ? bih1 : bhh1;
    int row = g * 64 + lane;
    f32x4 wt[16];                                  // 64 weight VGPRs
#pragma unroll
    for (int t = 0; t < 16; t++)
        wt[t] = ((const f32x4*)(W + (size_t)row * H))[t];
    float bias = Bv[row];

    float hreg0 = 0.0f, hreg1 = 0.0f;
    float hb4[4] = {0.f, 0.f, 0.f, 0.f};
    f32x4 xcr[4];                                  // xp ring: this wave's gate only
#pragma unroll
    for (int t = 0; t < 4; t++) xcr[t] = (f32x4){0.f, 0.f, 0.f, 0.f};
    const float* xpB = xpT + (size_t)b * 125 * GDIM * 4;

    // prefetch chunk c (4 steps of this wave's gate row) into ring slot c&3
    auto pre = [&](int c, int slot_unused) {
        if (c < 125)
            xcr[c & 3] = *(const f32x4*)(xpB + ((size_t)c * GDIM + g * 64 + lane) * 4);
    };

    if (wv < 3) { pre(0, 0); pre(1, 1); }
    __syncthreads();

    // full-K row dot: 16 uniform-addr b128 broadcasts + 64 FMAs, 4 indep acc chains
    auto mv = [&](const float* hb) -> float {
        float a0 = bias, a1 = 0.0f, a2 = 0.0f, a3 = 0.0f;
#pragma unroll
        for (int t = 0; t < 16; t++) {
            f32x4 h4 = ((const f32x4*)hb)[t];
            a0 += wt[t][0] * h4[0];
            a1 += wt[t][1] * h4[1];
            a2 += wt[t][2] * h4[2];
            a3 += wt[t][3] * h4[3];
        }
        return (a0 + a1) + (a2 + a3);
    };

    // e = u&3, compile-time at every call site (unrolled); xval = this wave's xp elem
    auto step = [&](int u, int e, float xval) {
        float an = 0.0f, xn_keep = 0.0f;
        // ---- phase 1 ----
        if (m == 0) {
            if (u < SEQ) {
                float a = mv(h0s[(e + 1) & 1]);            // Whh0_g @ h0[u-1] + bhh0_g
                if (g == 2) { an = a; xn_keep = xval; }
                else sg0[g][lane] = sigf(xval + a);
            }
        } else if (m == 1) {
            if (u >= 1 && u <= 500) {
                float a = mv(h0s[(e + 1) & 1]);            // Wih1_g @ h0[u-1] + bih1_g
                p1s[(e + 1) & 1][g][lane] = a;             // i1[u-1]
            }
        } else {
            if (u >= 2) {
                float a = mv(h1bc);                        // Whh1_g @ h1[u-3] + bhh1_g
                if (g == 2) an = a;
                else sg1[g][lane] = sigf(p1s[e & 1][g][lane] + a);
            }
        }
        BAR_LGKM();                                        // barrier 1: rg/zg visible
        // ---- phase 2: n-waves only ----
        if (wv == 2) {
            if (u < SEQ) {
                float ng = tanhfast(xn_keep + sg0[0][lane] * an);
                float zg = sg0[1][lane];
                hreg0 = (1.0f - zg) * ng + zg * hreg0;
                h0s[e & 1][lane] = hreg0;                  // h0[u]
            }
        } else if (wv == 8) {
            if (u >= 2) {
                float ng = tanhfast(p1s[e & 1][2][lane] + sg1[0][lane] * an);
                float zg = sg1[1][lane];
                hreg1 = (1.0f - zg) * ng + zg * hreg1;     // h1[u-2]
                h1bc[lane] = hreg1;
                hb4[(e + 2) & 3] = hreg1;                  // t=u-2, t&3=(e+2)&3
                if (e == 1) {                              // t&3==3: flush h1[u-5..u-2]
                    float* dst = hbuf + ((size_t)b * SEQ + (u - 5)) * H + lane;
#pragma unroll
                    for (int t = 0; t < 4; t++) dst[t * H] = hb4[t];
                }
            }
        }
        BAR_LGKM();                                        // barrier 2: h visible
    };

    for (int scb = 0; scb < 31; scb++) {
#pragma unroll
        for (int sci = 0; sci < 4; sci++) {
            int sc = scb * 4 + sci;
            if (wv < 3 && (sci & 1) == 0) {
                pre(sc + 2, 0);
                pre(sc + 3, 0);
            }
            int s0 = sc * 4;
            step(s0 + 0, 0, xcr[sci][0]);
            step(s0 + 1, 1, xcr[sci][1]);
            step(s0 + 2, 2, xcr[sci][2]);
            step(s0 + 3, 3, xcr[sci][3]);
        }
    }
    {   // sc = 124 (ring slot 0, loaded at sc=122): steps 496..499
        step(496, 0, xcr[0][0]);
        step(497, 1, xcr[0][1]);
        step(498, 2, xcr[0][2]);
        step(499, 3, xcr[0][3]);
    }
    // tail u = 500, 501: drain the skewed pipeline (m1 at 500, m2 at 500/501)
    step(500, 0, 0.0f);
    step(501, 1, 0.0f);
}

// ---------------- MFMA SINDy layer (unchanged) ---------------------------------------
__global__ __launch_bounds__(512) void sindy_mfma(float* __restrict__ hbuf,
                                                  const short* __restrict__ cpk,
                                                  const short* __restrict__ w1p,
                                                  const short* __restrict__ w2p,
                                                  const float* __restrict__ g1,
                                                  const float* __restrict__ b1n,
                                                  const float* __restrict__ bf1,
                                                  const float* __restrict__ bf2v,
                                                  const float* __restrict__ g2,
                                                  const float* __restrict__ b2n,
                                                  float* __restrict__ out,
                                                  int final_layer) {
    __shared__ float z[64 * 68];
    __shared__ float upd[64 * 68];
    __shared__ float ff[64 * 132];
    __shared__ unsigned kmap[KPAD];
    __shared__ float bfs1[FFD], bfs2[H], g1s[H], b1s[H], g2s[H], b2s[H];

    int tid = threadIdx.x;
    int wv = __builtin_amdgcn_readfirstlane(tid >> 6);
    int lane = tid & 63;
    int row0 = blockIdx.x * 64;

    for (int idx = tid; idx < 64 * 16; idx += 512) {
        int r = idx >> 4, c4 = idx & 15;
        *(f32x4*)&z[r * 68 + c4 * 4] = *(const f32x4*)&hbuf[(size_t)(row0 + r) * H + c4 * 4];
    }
    for (int idx = tid; idx < 64 * 17; idx += 512)
        *(f32x4*)&upd[idx * 4] = (f32x4){0.f, 0.f, 0.f, 0.f};
    if (tid < 64) {
        z[tid * 68 + 64] = 1.0f; z[tid * 68 + 65] = 0.0f;
        z[tid * 68 + 66] = 0.0f; z[tid * 68 + 67] = 0.0f;
    }
    for (int k = tid; k < KPAD; k += 512) {
        unsigned a, b;
        if (k == 0) { a = 64; b = 64; }
        else if (k < 1 + H) { a = (unsigned)(k - 1); b = 64; }
        else if (k < LIBN) {
            int qq = k - (1 + H);
            double s = sqrt(16641.0 - 8.0 * (double)qq);
            int i = (int)((129.0 - s) * 0.5);
            int base = 64 * i - (i * (i - 1)) / 2;
            a = (unsigned)i; b = (unsigned)(i + (qq - base));
        } else { a = 65; b = 65; }
        kmap[k] = (a << 16) | b;
    }
    if (tid < FFD) bfs1[tid] = bf1[tid];
    if (tid < H) {
        bfs2[tid] = bf2v[tid];
        g1s[tid] = g1[tid]; b1s[tid] = b1n[tid];
        g2s[tid] = g2[tid]; b2s[tid] = b2n[tid];
    }
    __syncthreads();

    int kj0 = ((lane >> 4) << 3);
    int m0 = (wv & 3) * 16;
    int m = m0 + (lane & 15);
    int rbase = m0 + ((lane >> 4) << 2);
    int cb16 = lane & 15;
    const float* zrow = &z[m * 68];

    // ---- phase 1: upd = theta @ coef (k-split 2-way) ----
    {
        int p = wv >> 2;
        f32x4 acc[4] = {{0,0,0,0},{0,0,0,0},{0,0,0,0},{0,0,0,0}};
        for (int kc = p; kc < NKC; kc += 2) {
            int kbase = kc * 32 + kj0;
            u32x4 km0 = *(const u32x4*)&kmap[kbase];
            u32x4 km1 = *(const u32x4*)&kmap[kbase + 4];
            short8 af;
            af[0] = bf16r(zrow[km0[0] >> 16] * zrow[km0[0] & 0xffff]);
            af[1] = bf16r(zrow[km0[1] >> 16] * zrow[km0[1] & 0xffff]);
            af[2] = bf16r(zrow[km0[2] >> 16] * zrow[km0[2] & 0xffff]);
            af[3] = bf16r(zrow[km0[3] >> 16] * zrow[km0[3] & 0xffff]);
            af[4] = bf16r(zrow[km1[0] >> 16] * zrow[km1[0] & 0xffff]);
            af[5] = bf16r(zrow[km1[1] >> 16] * zrow[km1[1] & 0xffff]);
            af[6] = bf16r(zrow[km1[2] >> 16] * zrow[km1[2] & 0xffff]);
            af[7] = bf16r(zrow[km1[3] >> 16] * zrow[km1[3] & 0xffff]);
            const short* cb = cpk + ((size_t)(kc * 4) * 64 + lane) * 8;
#pragma unroll
            for (int nt = 0; nt < 4; nt++) {
                short8 bf = *(const short8*)(cb + (size_t)nt * 512);
                acc[nt] = __builtin_amdgcn_mfma_f32_16x16x32_bf16(af, bf, acc[nt], 0, 0, 0);
            }
        }
#pragma unroll
        for (int nt = 0; nt < 4; nt++)
#pragma unroll
            for (int r = 0; r < 4; r++)
                atomicAdd(&upd[(rbase + r) * 68 + nt * 16 + cb16], acc[nt][r]);
    }
    __syncthreads();

    // ---- phase 2: LN1 (wave 0) -> z ----
    if (wv == 0) {
        float v[64];
        float s1 = 0.0f;
#pragma unroll
        for (int c = 0; c < 64; c++) { v[c] = z[lane * 68 + c] + upd[lane * 68 + c]; s1 += v[c]; }
        float mn = s1 * (1.0f / 64.0f);
        float s2 = 0.0f;
#pragma unroll
        for (int c = 0; c < 64; c++) { float d = v[c] - mn; s2 += d * d; }
        float rstd = 1.0f / sqrtf(s2 * (1.0f / 64.0f) + 1e-5f);
#pragma unroll
        for (int c = 0; c < 64; c++)
            z[lane * 68 + c] = (v[c] - mn) * rstd * g1s[c] + b1s[c];
    }
    __syncthreads();

    // ---- phase 3: ff = gelu(LN1 @ W1^T + b1) ----
    {
        int nq = wv >> 2;
        f32x4 acc[4] = {{0,0,0,0},{0,0,0,0},{0,0,0,0},{0,0,0,0}};
#pragma unroll
        for (int kc = 0; kc < 2; kc++) {
            f32x4 za = *(const f32x4*)&z[m * 68 + kc * 32 + kj0];
            f32x4 zb = *(const f32x4*)&z[m * 68 + kc * 32 + kj0 + 4];
            short8 af;
            af[0] = bf16r(za[0]); af[1] = bf16r(za[1]); af[2] = bf16r(za[2]); af[3] = bf16r(za[3]);
            af[4] = bf16r(zb[0]); af[5] = bf16r(zb[1]); af[6] = bf16r(zb[2]); af[7] = bf16r(zb[3]);
#pragma unroll
            for (int t = 0; t < 4; t++) {
                int nt = nq * 4 + t;
                short8 bf = *(const short8*)(w1p + ((size_t)(kc * 8 + nt) * 64 + lane) * 8);
                acc[t] = __builtin_amdgcn_mfma_f32_16x16x32_bf16(af, bf, acc[t], 0, 0, 0);
            }
        }
#pragma unroll
        for (int t = 0; t < 4; t++) {
            int col = (nq * 4 + t) * 16 + cb16;
#pragma unroll
            for (int r = 0; r < 4; r++) {
                float v = acc[t][r] + bfs1[col];
                ff[(rbase + r) * 132 + col] = 0.5f * v * (1.0f + erff(v * 0.70710678118654752f));
            }
        }
    }
    __syncthreads();

    // ---- phase 5: upd = ff @ W2^T + b2 ----
    {
        int nh = wv >> 2;
        f32x4 acc[2] = {{0,0,0,0},{0,0,0,0}};
        const float* frow = &ff[m * 132];
#pragma unroll
        for (int kc = 0; kc < 4; kc++) {
            f32x4 fa = *(const f32x4*)&frow[kc * 32 + kj0];
            f32x4 fb = *(const f32x4*)&frow[kc * 32 + kj0 + 4];
            short8 af;
            af[0] = bf16r(fa[0]); af[1] = bf16r(fa[1]); af[2] = bf16r(fa[2]); af[3] = bf16r(fa[3]);
            af[4] = bf16r(fb[0]); af[5] = bf16r(fb[1]); af[6] = bf16r(fb[2]); af[7] = bf16r(fb[3]);
#pragma unroll
            for (int t = 0; t < 2; t++) {
                int nt = nh * 2 + t;
                short8 bf = *(const short8*)(w2p + ((size_t)(kc * 4 + nt) * 64 + lane) * 8);
                acc[t] = __builtin_amdgcn_mfma_f32_16x16x32_bf16(af, bf, acc[t], 0, 0, 0);
            }
        }
#pragma unroll
        for (int t = 0; t < 2; t++) {
            int col = (nh * 2 + t) * 16 + cb16;
#pragma unroll
            for (int r = 0; r < 4; r++)
                upd[(rbase + r) * 68 + col] = acc[t][r] + bfs2[col];
        }
    }
    __syncthreads();

    // ---- phase 6: LN2 + write (wave 0) ----
    if (wv == 0) {
        float v[64];
        float s1 = 0.0f;
#pragma unroll
        for (int c = 0; c < 64; c++) { v[c] = z[lane * 68 + c] + upd[lane * 68 + c]; s1 += v[c]; }
        float mn = s1 * (1.0f / 64.0f);
        float s2 = 0.0f;
#pragma unroll
        for (int c = 0; c < 64; c++) { float d = v[c] - mn; s2 += d * d; }
        float rstd = 1.0f / sqrtf(s2 * (1.0f / 64.0f) + 1e-5f);
        int row = row0 + lane;
#pragma unroll
        for (int c = 0; c < 64; c++) {
            float res = (v[c] - mn) * rstd * g2s[c] + b2s[c];
            if (!final_layer) {
                hbuf[(size_t)row * H + c] = res;
            } else {
                out[(size_t)row * H + c] = res;
                if (row % SEQ == SEQ - 1)
                    out[(size_t)NROW * H + (row / SEQ) * H + c] = res;
            }
        }
    }
}

extern "C" void kernel_launch(void* const* d_in, const int* in_sizes, int n_in,
                              void* d_out, int out_size, void* d_ws, size_t ws_size,
                              hipStream_t stream) {
    const float* x    = (const float*)d_in[0];
    const float* wih0 = (const float*)d_in[1];
    const float* whh0 = (const float*)d_in[2];
    const float* bih0 = (const float*)d_in[3];
    const float* bhh0 = (const float*)d_in[4];
    const float* wih1 = (const float*)d_in[5];
    const float* whh1 = (const float*)d_in[6];
    const float* bih1 = (const float*)d_in[7];
    const float* bhh1 = (const float*)d_in[8];
    const float* coeffs = (const float*)d_in[9];
    const float* ln1g = (const float*)d_in[10];
    const float* ln1b = (const float*)d_in[11];
    const float* w1   = (const float*)d_in[12];
    const float* b1   = (const float*)d_in[13];
    const float* w2   = (const float*)d_in[14];
    const float* b2   = (const float*)d_in[15];
    const float* ln2g = (const float*)d_in[16];
    const float* ln2b = (const float*)d_in[17];

    float* out = (float*)d_out;
    float* ws  = (float*)d_ws;
    float* xpT = ws;                               // 16000*192 = 3,072,000 floats
    float* wtp = ws + (size_t)NROW * GDIM;         // 24,576 floats
    short* bfa = (short*)(wtp + GDIM * DM);        // bf16 fragment area
    short* cpk[2] = { bfa, bfa + 139264 };
    short* w1pk[2] = { bfa + 2 * 139264, bfa + 2 * 139264 + 8192 };
    short* w2pk[2] = { bfa + 2 * 139264 + 2 * 8192, bfa + 2 * 139264 + 3 * 8192 };
    float* hbuf = out;                             // reuse first 1,024,000 floats of d_out

    pack_wih0<<<(GDIM * DM + 255) / 256, 256, 0, stream>>>(wih0, wtp);
    for (int l = 0; l < 2; l++) {
        pack_coef_frag<<<139264 / 256, 256, 0, stream>>>(coeffs + (size_t)l * LIBN * H, cpk[l]);
        pack_w1_frag<<<8192 / 256, 256, 0, stream>>>(w1 + (size_t)l * FFD * H, w1pk[l]);
        pack_w2_frag<<<8192 / 256, 256, 0, stream>>>(w2 + (size_t)l * H * FFD, w2pk[l]);
    }
    xp0_gemm<<<NROW / 64, 192, 0, stream>>>(x, wtp, bih0, xpT);
    gru_fused<<<BSZ, 576, 0, stream>>>(xpT, whh0, bhh0, wih1, bih1, whh1, bhh1, hbuf);
    for (int l = 0; l < 2; l++) {
        sindy_mfma<<<NROW / 64, 512, 0, stream>>>(
            hbuf, cpk[l], w1pk[l], w2pk[l],
            ln1g + l * H, ln1b + l * H, b1 + l * FFD,
            b2 + l * H, ln2g + l * H, ln2b + l * H,
            out, l == 1);
    }
}

// Round 6
// 566.465 us; speedup vs baseline: 1.3654x; 1.3210x over previous
//
#include <hip/hip_runtime.h>
#include <hip/hip_bf16.h>
#include <math.h>

#define H 64
#define DM 128
#define GDIM 192      // 3*H
#define BSZ 32
#define SEQ 500
#define NROW (BSZ*SEQ)  // 16000
#define LIBN 2145
#define FFD 128
#define NKC2 75       // padded grouped-K chunks of 32 (2400 slots, 300 groups)
#define NGRP 300

typedef __attribute__((ext_vector_type(8))) short short8;   // bf16x8 MFMA operand
typedef __attribute__((ext_vector_type(4))) float f32x4;    // MFMA accumulator
typedef __attribute__((ext_vector_type(4))) unsigned u32x4;

__device__ __forceinline__ float sigf(float x) {
    return 1.0f / (1.0f + __expf(-x));
}
__device__ __forceinline__ float tanhfast(float x) {
    x = fminf(fmaxf(x, -15.0f), 15.0f);
    float t = __expf(-2.0f * x);
    return (1.0f - t) / (1.0f + t);
}
__device__ __forceinline__ short bf16r(float f) {   // fp32 -> bf16 rne
    unsigned u = __float_as_uint(f);
    unsigned r = (u + 0x7fffu + ((u >> 16) & 1u)) >> 16;
    return (short)r;
}

// decode grouped-K group id -> (a, b): af[j] = z[a] * z[b + j], j = 0..7
__device__ __forceinline__ void grp_decode(int g, int& a, int& b) {
    if (g < 8) { a = 64; b = g * 8; }                 // linear: 1 * z[8g..8g+7]
    else if (g == 8 || g >= 297) { a = 64; b = 64; }  // const slot / padding
    else {
        int G = g - 9, acc = 0;
        a = 0; b = 0;
        for (int i2 = 0; i2 < 64; i2++) {
            int cnt = 8 - (i2 >> 3);                  // aligned 8-groups covering [i2,63]
            if (G < acc + cnt) { a = i2; b = ((i2 >> 3) + (G - acc)) * 8; break; }
            acc += cnt;
        }
    }
}

// ---------------- pack Wih0 (192,128) -> WTp[k4][g][e] for coalesced float4 loads ----
__global__ void pack_wih0(const float* __restrict__ w, float* __restrict__ wt) {
    int idx = blockIdx.x * 256 + threadIdx.x;
    if (idx >= GDIM * DM) return;
    int e  = idx & 3;
    int g  = (idx >> 2) % GDIM;
    int k4 = idx / (GDIM * 4);
    wt[idx] = w[g * DM + k4 * 4 + e];
}

// ---- prepack coef into bf16 B-fragments in the GROUPED padded K-order ----
// k' = kc*32 + (lane>>4)*8 + j belongs to group g = kc*4 + (lane>>4), slot jj = j.
// group (a,b): theta slot = z[a]*z[b+jj]; coef row: linear g<8 -> 1+8g+jj;
// const g==8 -> row 0 at jj==0; quad -> 65 + qbase(i) + (j-i) iff j>=i; else 0.
__global__ void pack_coef_frag2(const float* __restrict__ coef, short* __restrict__ cp) {
    int idx = blockIdx.x * 256 + threadIdx.x;           // 75*4*64*8 = 153600
    int j = idx & 7, lane = (idx >> 3) & 63, nt = (idx >> 9) & 3, kc = idx >> 11;
    int grp = kc * 4 + (lane >> 4);
    int row = -1;
    if (grp < 8) row = 1 + grp * 8 + j;
    else if (grp == 8) row = (j == 0) ? 0 : -1;
    else if (grp < 297) {
        int a, b;
        grp_decode(grp, a, b);
        int jdx = b + j;
        if (jdx >= a) row = 65 + a * 64 - (a * (a - 1)) / 2 + (jdx - a);
    }
    int c = nt * 16 + (lane & 15);
    cp[idx] = (row >= 0) ? bf16r(coef[(size_t)row * H + c]) : (short)0;
}
// ---- W1 (128,64): B = W1^T (K=64,N=128) ----
__global__ void pack_w1_frag(const float* __restrict__ w1, short* __restrict__ wp) {
    int idx = blockIdx.x * 256 + threadIdx.x;           // 2*8*64*8 = 8192
    int j = idx & 7, lane = (idx >> 3) & 63, nt = (idx >> 9) & 7, kc = idx >> 12;
    int k = kc * 32 + ((lane >> 4) << 3) + j;
    int n = nt * 16 + (lane & 15);
    wp[idx] = bf16r(w1[(size_t)n * H + k]);
}
// ---- W2 (64,128): B = W2^T (K=128,N=64) ----
__global__ void pack_w2_frag(const float* __restrict__ w2, short* __restrict__ wp) {
    int idx = blockIdx.x * 256 + threadIdx.x;           // 4*4*64*8 = 8192
    int j = idx & 7, lane = (idx >> 3) & 63, nt = (idx >> 9) & 3, kc = idx >> 11;
    int k = kc * 32 + ((lane >> 4) << 3) + j;
    int n = nt * 16 + (lane & 15);
    wp[idx] = bf16r(w2[(size_t)n * FFD + k]);
}

// ---------------- xp0 = x @ Wih0^T + bih0, stored in GRU chunk layout ----------------
__global__ __launch_bounds__(192, 2) void xp0_gemm(const float* __restrict__ x,
                                                   const float* __restrict__ wtp,
                                                   const float* __restrict__ bih0,
                                                   float* __restrict__ xpT) {
    __shared__ float xs[64][DM];
    int rb = blockIdx.x * 64;
    for (int idx = threadIdx.x; idx < 64 * 32; idx += 192) {
        int r = idx >> 5, k4 = idx & 31;
        ((f32x4*)xs[r])[k4] = ((const f32x4*)(x + (size_t)(rb + r) * DM))[k4];
    }
    __syncthreads();
    int g = threadIdx.x;
    float bias = bih0[g];
    float acc[64];
#pragma unroll
    for (int r = 0; r < 64; r++) acc[r] = bias;
    for (int k4 = 0; k4 < 32; k4++) {
        f32x4 w4 = ((const f32x4*)wtp)[k4 * GDIM + g];
#pragma unroll
        for (int r = 0; r < 64; r++) {
            f32x4 xv = ((f32x4*)xs[r])[k4];
            acc[r] += w4[0] * xv[0] + w4[1] * xv[1] + w4[2] * xv[2] + w4[3] * xv[3];
        }
    }
    for (int r = 0; r < 64; r++) {
        int row = rb + r;
        int bb = row / 500;
        int ss = row - bb * 500;
        xpT[(((size_t)bb * 125 + (ss >> 2)) * GDIM + g) * 4 + (ss & 3)] = acc[r];
    }
}

// ---------------- fused 2-layer GRU scan: R0 12-wave structure (306 µs, verified) ----
// Wave (m = wv%3, q = wv/3) computes K-chunk [16q,16q+16) of matvec m (m0: Whh0@h0,
// m1: Wih1@h0, m2: Whh1@h1); lane i owns rows {i,64+i,128+i}. Gate waves: wv0 = layer0,
// wv2 = layer1 (one step skewed). xp inputs read 2 chunks (8 steps) ahead into a
// 4-buffer register ring; h1 outputs buffered 4 steps in regs.
__global__ __launch_bounds__(768, 3) void gru_fused(const float* __restrict__ xpT,
                                                    const float* __restrict__ whh0,
                                                    const float* __restrict__ bhh0,
                                                    const float* __restrict__ wih1,
                                                    const float* __restrict__ bih1,
                                                    const float* __restrict__ whh1,
                                                    const float* __restrict__ bhh1,
                                                    float* __restrict__ hbuf) {
    int b = blockIdx.x;
    int tid = threadIdx.x;
    int wv = __builtin_amdgcn_readfirstlane(tid >> 6);
    int lane = tid & 63;
    int m = wv % 3;
    int q = wv / 3;
    int k0 = q * 16;

    __shared__ __align__(16) float h0s[H];
    __shared__ __align__(16) float h1s[H];
    __shared__ float part[3][4][GDIM];

    if (tid < H) { h0s[tid] = 0.0f; h1s[tid] = 0.0f; }

    const float* W = (m == 0) ? whh0 : (m == 1) ? wih1 : whh1;
    float wr[16], wz[16], wn[16];
#pragma unroll
    for (int k4 = 0; k4 < 4; k4++) {
        f32x4 a = ((const f32x4*)(W + (size_t)lane * H + k0))[k4];
        f32x4 c = ((const f32x4*)(W + (size_t)(H + lane) * H + k0))[k4];
        f32x4 d = ((const f32x4*)(W + (size_t)(2 * H + lane) * H + k0))[k4];
        wr[4*k4] = a[0]; wr[4*k4+1] = a[1]; wr[4*k4+2] = a[2]; wr[4*k4+3] = a[3];
        wz[4*k4] = c[0]; wz[4*k4+1] = c[1]; wz[4*k4+2] = c[2]; wz[4*k4+3] = c[3];
        wn[4*k4] = d[0]; wn[4*k4+1] = d[1]; wn[4*k4+2] = d[2]; wn[4*k4+3] = d[3];
    }

    float b0r = 0, b0z = 0, b0n = 0;
    float b1ir = 0, b1iz = 0, b1in = 0, b1hr = 0, b1hz = 0, b1hn = 0;
    float hreg0 = 0.0f, hreg1 = 0.0f;
    float hb4[4] = {0.f, 0.f, 0.f, 0.f};
    f32x4 xc[4][3];
    const float* xpB = xpT + (size_t)b * 125 * GDIM * 4;

    if (wv == 0) {
        b0r = bhh0[lane]; b0z = bhh0[H + lane]; b0n = bhh0[2 * H + lane];
#pragma unroll
        for (int g3 = 0; g3 < 3; g3++) {
            xc[0][g3] = *(const f32x4*)(xpB + ((size_t)0 * GDIM + g3 * 64 + lane) * 4);
            xc[1][g3] = *(const f32x4*)(xpB + ((size_t)1 * GDIM + g3 * 64 + lane) * 4);
        }
    } else if (wv == 2) {
        b1ir = bih1[lane]; b1iz = bih1[H + lane]; b1in = bih1[2 * H + lane];
        b1hr = bhh1[lane]; b1hz = bhh1[H + lane]; b1hn = bhh1[2 * H + lane];
    }
    __syncthreads();

    auto loadch = [&](int c, int buf) {
        if (c < 125) {
#pragma unroll
            for (int g3 = 0; g3 < 3; g3++)
                xc[buf][g3] = *(const f32x4*)(xpB + ((size_t)c * GDIM + g3 * 64 + lane) * 4);
        }
    };

    auto step = [&](int s, int e, float xr, float xz, float xn) {
        // phase 1: partial matvec over K-chunk [k0, k0+16); h reads are wave-uniform
        // addresses -> LDS broadcast (no bandwidth serialization).
        const float* hv = (m == 2) ? h1s : h0s;
        float ar = 0, az = 0, an = 0;
#pragma unroll
        for (int t4 = 0; t4 < 4; t4++) {
            f32x4 h4 = ((const f32x4*)(hv + k0))[t4];
            ar += wr[4*t4] * h4[0] + wr[4*t4+1] * h4[1] + wr[4*t4+2] * h4[2] + wr[4*t4+3] * h4[3];
            az += wz[4*t4] * h4[0] + wz[4*t4+1] * h4[1] + wz[4*t4+2] * h4[2] + wz[4*t4+3] * h4[3];
            an += wn[4*t4] * h4[0] + wn[4*t4+1] * h4[1] + wn[4*t4+2] * h4[2] + wn[4*t4+3] * h4[3];
        }
        part[m][q][lane] = ar;
        part[m][q][H + lane] = az;
        part[m][q][2 * H + lane] = an;
        __syncthreads();

        // phase 2: gates
        if (wv == 0) {
            if (s < SEQ) {
                float gr = b0r, gz = b0z, gn = b0n;
#pragma unroll
                for (int qq = 0; qq < 4; qq++) {
                    gr += part[0][qq][lane];
                    gz += part[0][qq][H + lane];
                    gn += part[0][qq][2 * H + lane];
                }
                float rg = sigf(xr + gr);
                float zg = sigf(xz + gz);
                float ng = tanhfast(xn + rg * gn);
                hreg0 = (1.0f - zg) * ng + zg * hreg0;
                h0s[lane] = hreg0;
            }
        } else if (wv == 2) {
            if (s >= 1) {
                float xr1 = b1ir, xz1 = b1iz, xn1 = b1in;
                float gr1 = b1hr, gz1 = b1hz, gn1 = b1hn;
#pragma unroll
                for (int qq = 0; qq < 4; qq++) {
                    xr1 += part[1][qq][lane];
                    xz1 += part[1][qq][H + lane];
                    xn1 += part[1][qq][2 * H + lane];
                    gr1 += part[2][qq][lane];
                    gz1 += part[2][qq][H + lane];
                    gn1 += part[2][qq][2 * H + lane];
                }
                float rg = sigf(xr1 + gr1);
                float zg = sigf(xz1 + gz1);
                float ng = tanhfast(xn1 + rg * gn1);
                hreg1 = (1.0f - zg) * ng + zg * hreg1;
                h1s[lane] = hreg1;
                hb4[(e + 3) & 3] = hreg1;                 // h1[s-1], (s-1)&3 == (e+3)&3
                if (e == 0) {                              // s in {4,8,...,500}: flush h1[s-4..s-1]
                    float* dst = hbuf + ((size_t)b * SEQ + (s - 4)) * H + lane;
#pragma unroll
                    for (int t = 0; t < 4; t++) dst[t * H] = hb4[t];
                }
            }
        }
        __syncthreads();
    };

    for (int scb = 0; scb < 31; scb++) {
#pragma unroll
        for (int sci = 0; sci < 4; sci++) {
            int sc = scb * 4 + sci;
            if (wv == 0 && (sci & 1) == 0) {
                loadch(sc + 2, (sci + 2) & 3);
                loadch(sc + 3, (sci + 3) & 3);
            }
            int s0 = sc * 4;
            step(s0 + 0, 0, xc[sci][0][0], xc[sci][1][0], xc[sci][2][0]);
            step(s0 + 1, 1, xc[sci][0][1], xc[sci][1][1], xc[sci][2][1]);
            step(s0 + 2, 2, xc[sci][0][2], xc[sci][1][2], xc[sci][2][2]);
            step(s0 + 3, 3, xc[sci][0][3], xc[sci][1][3], xc[sci][2][3]);
        }
    }
    {   // sc = 124 (buf 0, loaded at sc=122)
        step(496, 0, xc[0][0][0], xc[0][1][0], xc[0][2][0]);
        step(497, 1, xc[0][0][1], xc[0][1][1], xc[0][2][1]);
        step(498, 2, xc[0][0][2], xc[0][1][2], xc[0][2][2]);
        step(499, 3, xc[0][0][3], xc[0][1][3], xc[0][2][3]);
    }
    // tail s = 500: produces h1[499] and flushes h1[496..499]
    step(500, 0, 0.0f, 0.0f, 0.0f);
}

// ---------------- MFMA SINDy layer: grouped-K theta build (4 LDS ops/chunk) ----------
__global__ __launch_bounds__(512) void sindy_mfma(float* __restrict__ hbuf,
                                                  const short* __restrict__ cpk,
                                                  const short* __restrict__ w1p,
                                                  const short* __restrict__ w2p,
                                                  const float* __restrict__ g1,
                                                  const float* __restrict__ b1n,
                                                  const float* __restrict__ bf1,
                                                  const float* __restrict__ bf2v,
                                                  const float* __restrict__ g2,
                                                  const float* __restrict__ b2n,
                                                  float* __restrict__ out,
                                                  int final_layer) {
    __shared__ float z[65 * 68];                   // row 64 = zero pad (safe b-reads)
    __shared__ float upd[64 * 68];
    __shared__ float ff[64 * 132];
    __shared__ unsigned kmap2[NGRP];               // per-group (a<<16)|b
    __shared__ float bfs1[FFD], bfs2[H], g1s[H], b1s[H], g2s[H], b2s[H];

    int tid = threadIdx.x;
    int wv = __builtin_amdgcn_readfirstlane(tid >> 6);
    int lane = tid & 63;
    int row0 = blockIdx.x * 64;

    for (int idx = tid; idx < 64 * 16; idx += 512) {
        int r = idx >> 4, c4 = idx & 15;
        *(f32x4*)&z[r * 68 + c4 * 4] = *(const f32x4*)&hbuf[(size_t)(row0 + r) * H + c4 * 4];
    }
    for (int idx = tid; idx < 64 * 17; idx += 512)
        *(f32x4*)&upd[idx * 4] = (f32x4){0.f, 0.f, 0.f, 0.f};
    if (tid < 64) {
        z[tid * 68 + 64] = 1.0f; z[tid * 68 + 65] = 0.0f;
        z[tid * 68 + 66] = 0.0f; z[tid * 68 + 67] = 0.0f;
    }
    if (tid < 68) z[64 * 68 + tid] = 0.0f;         // zero pad row
    if (tid < NGRP) {
        int a, b;
        grp_decode(tid, a, b);
        kmap2[tid] = ((unsigned)a << 16) | (unsigned)b;
    }
    if (tid < FFD) bfs1[tid] = bf1[tid];
    if (tid < H) {
        bfs2[tid] = bf2v[tid];
        g1s[tid] = g1[tid]; b1s[tid] = b1n[tid];
        g2s[tid] = g2[tid]; b2s[tid] = b2n[tid];
    }
    __syncthreads();

    int kj0 = ((lane >> 4) << 3);
    int m0 = (wv & 3) * 16;
    int m = m0 + (lane & 15);
    int rbase = m0 + ((lane >> 4) << 2);
    int cb16 = lane & 15;
    const float* zrow = &z[m * 68];

    // ---- phase 1: upd = theta @ coef (grouped-K, k-split 2-way) ----
    // per chunk per lane: 1 u32 + 1 scalar + 2 aligned b128 LDS reads (was 18 ops):
    // af[j] = z[a] * z[b+j]; zero-coef slots absorb j<i and padding.
    {
        int p = wv >> 2;
        f32x4 acc[4] = {{0,0,0,0},{0,0,0,0},{0,0,0,0},{0,0,0,0}};
        for (int kc = p; kc < NKC2; kc += 2) {
            unsigned ab = kmap2[kc * 4 + (lane >> 4)];
            float za = zrow[ab >> 16];
            const float* zb = &zrow[ab & 0xffffu];
            f32x4 z0 = *(const f32x4*)zb;
            f32x4 z1 = *(const f32x4*)(zb + 4);
            short8 af;
            af[0] = bf16r(za * z0[0]);
            af[1] = bf16r(za * z0[1]);
            af[2] = bf16r(za * z0[2]);
            af[3] = bf16r(za * z0[3]);
            af[4] = bf16r(za * z1[0]);
            af[5] = bf16r(za * z1[1]);
            af[6] = bf16r(za * z1[2]);
            af[7] = bf16r(za * z1[3]);
            const short* cb = cpk + ((size_t)(kc * 4) * 64 + lane) * 8;
#pragma unroll
            for (int nt = 0; nt < 4; nt++) {
                short8 bf = *(const short8*)(cb + (size_t)nt * 512);
                acc[nt] = __builtin_amdgcn_mfma_f32_16x16x32_bf16(af, bf, acc[nt], 0, 0, 0);
            }
        }
#pragma unroll
        for (int nt = 0; nt < 4; nt++)
#pragma unroll
            for (int r = 0; r < 4; r++)
                atomicAdd(&upd[(rbase + r) * 68 + nt * 16 + cb16], acc[nt][r]);
    }
    __syncthreads();

    // ---- phase 2: LN1 (wave 0) -> z ----
    if (wv == 0) {
        float v[64];
        float s1 = 0.0f;
#pragma unroll
        for (int c = 0; c < 64; c++) { v[c] = z[lane * 68 + c] + upd[lane * 68 + c]; s1 += v[c]; }
        float mn = s1 * (1.0f / 64.0f);
        float s2 = 0.0f;
#pragma unroll
        for (int c = 0; c < 64; c++) { float d = v[c] - mn; s2 += d * d; }
        float rstd = 1.0f / sqrtf(s2 * (1.0f / 64.0f) + 1e-5f);
#pragma unroll
        for (int c = 0; c < 64; c++)
            z[lane * 68 + c] = (v[c] - mn) * rstd * g1s[c] + b1s[c];
    }
    __syncthreads();

    // ---- phase 3: ff = gelu(LN1 @ W1^T + b1) ----
    {
        int nq = wv >> 2;
        f32x4 acc[4] = {{0,0,0,0},{0,0,0,0},{0,0,0,0},{0,0,0,0}};
#pragma unroll
        for (int kc = 0; kc < 2; kc++) {
            f32x4 za = *(const f32x4*)&z[m * 68 + kc * 32 + kj0];
            f32x4 zb = *(const f32x4*)&z[m * 68 + kc * 32 + kj0 + 4];
            short8 af;
            af[0] = bf16r(za[0]); af[1] = bf16r(za[1]); af[2] = bf16r(za[2]); af[3] = bf16r(za[3]);
            af[4] = bf16r(zb[0]); af[5] = bf16r(zb[1]); af[6] = bf16r(zb[2]); af[7] = bf16r(zb[3]);
#pragma unroll
            for (int t = 0; t < 4; t++) {
                int nt = nq * 4 + t;
                short8 bf = *(const short8*)(w1p + ((size_t)(kc * 8 + nt) * 64 + lane) * 8);
                acc[t] = __builtin_amdgcn_mfma_f32_16x16x32_bf16(af, bf, acc[t], 0, 0, 0);
            }
        }
#pragma unroll
        for (int t = 0; t < 4; t++) {
            int col = (nq * 4 + t) * 16 + cb16;
#pragma unroll
            for (int r = 0; r < 4; r++) {
                float v = acc[t][r] + bfs1[col];
                ff[(rbase + r) * 132 + col] = 0.5f * v * (1.0f + erff(v * 0.70710678118654752f));
            }
        }
    }
    __syncthreads();

    // ---- phase 5: upd = ff @ W2^T + b2 ----
    {
        int nh = wv >> 2;
        f32x4 acc[2] = {{0,0,0,0},{0,0,0,0}};
        const float* frow = &ff[m * 132];
#pragma unroll
        for (int kc = 0; kc < 4; kc++) {
            f32x4 fa = *(const f32x4*)&frow[kc * 32 + kj0];
            f32x4 fb = *(const f32x4*)&frow[kc * 32 + kj0 + 4];
            short8 af;
            af[0] = bf16r(fa[0]); af[1] = bf16r(fa[1]); af[2] = bf16r(fa[2]); af[3] = bf16r(fa[3]);
            af[4] = bf16r(fb[0]); af[5] = bf16r(fb[1]); af[6] = bf16r(fb[2]); af[7] = bf16r(fb[3]);
#pragma unroll
            for (int t = 0; t < 2; t++) {
                int nt = nh * 2 + t;
                short8 bf = *(const short8*)(w2p + ((size_t)(kc * 4 + nt) * 64 + lane) * 8);
                acc[t] = __builtin_amdgcn_mfma_f32_16x16x32_bf16(af, bf, acc[t], 0, 0, 0);
            }
        }
#pragma unroll
        for (int t = 0; t < 2; t++) {
            int col = (nh * 2 + t) * 16 + cb16;
#pragma unroll
            for (int r = 0; r < 4; r++)
                upd[(rbase + r) * 68 + col] = acc[t][r] + bfs2[col];
        }
    }
    __syncthreads();

    // ---- phase 6: LN2 + write (wave 0) ----
    if (wv == 0) {
        float v[64];
        float s1 = 0.0f;
#pragma unroll
        for (int c = 0; c < 64; c++) { v[c] = z[lane * 68 + c] + upd[lane * 68 + c]; s1 += v[c]; }
        float mn = s1 * (1.0f / 64.0f);
        float s2 = 0.0f;
#pragma unroll
        for (int c = 0; c < 64; c++) { float d = v[c] - mn; s2 += d * d; }
        float rstd = 1.0f / sqrtf(s2 * (1.0f / 64.0f) + 1e-5f);
        int row = row0 + lane;
#pragma unroll
        for (int c = 0; c < 64; c++) {
            float res = (v[c] - mn) * rstd * g2s[c] + b2s[c];
            if (!final_layer) {
                hbuf[(size_t)row * H + c] = res;
            } else {
                out[(size_t)row * H + c] = res;
                if (row % SEQ == SEQ - 1)
                    out[(size_t)NROW * H + (row / SEQ) * H + c] = res;
            }
        }
    }
}

extern "C" void kernel_launch(void* const* d_in, const int* in_sizes, int n_in,
                              void* d_out, int out_size, void* d_ws, size_t ws_size,
                              hipStream_t stream) {
    const float* x    = (const float*)d_in[0];
    const float* wih0 = (const float*)d_in[1];
    const float* whh0 = (const float*)d_in[2];
    const float* bih0 = (const float*)d_in[3];
    const float* bhh0 = (const float*)d_in[4];
    const float* wih1 = (const float*)d_in[5];
    const float* whh1 = (const float*)d_in[6];
    const float* bih1 = (const float*)d_in[7];
    const float* bhh1 = (const float*)d_in[8];
    const float* coeffs = (const float*)d_in[9];
    const float* ln1g = (const float*)d_in[10];
    const float* ln1b = (const float*)d_in[11];
    const float* w1   = (const float*)d_in[12];
    const float* b1   = (const float*)d_in[13];
    const float* w2   = (const float*)d_in[14];
    const float* b2   = (const float*)d_in[15];
    const float* ln2g = (const float*)d_in[16];
    const float* ln2b = (const float*)d_in[17];

    float* out = (float*)d_out;
    float* ws  = (float*)d_ws;
    float* xpT = ws;                               // 16000*192 = 3,072,000 floats
    float* wtp = ws + (size_t)NROW * GDIM;         // 24,576 floats
    short* bfa = (short*)(wtp + GDIM * DM);        // bf16 fragment area
    const int CPK2 = NKC2 * 4 * 64 * 8;            // 153600 shorts per layer
    short* cpk[2] = { bfa, bfa + CPK2 };
    short* w1pk[2] = { bfa + 2 * CPK2, bfa + 2 * CPK2 + 8192 };
    short* w2pk[2] = { bfa + 2 * CPK2 + 2 * 8192, bfa + 2 * CPK2 + 3 * 8192 };
    float* hbuf = out;                             // reuse first 1,024,000 floats of d_out

    pack_wih0<<<(GDIM * DM + 255) / 256, 256, 0, stream>>>(wih0, wtp);
    for (int l = 0; l < 2; l++) {
        pack_coef_frag2<<<CPK2 / 256, 256, 0, stream>>>(coeffs + (size_t)l * LIBN * H, cpk[l]);
        pack_w1_frag<<<8192 / 256, 256, 0, stream>>>(w1 + (size_t)l * FFD * H, w1pk[l]);
        pack_w2_frag<<<8192 / 256, 256, 0, stream>>>(w2 + (size_t)l * H * FFD, w2pk[l]);
    }
    xp0_gemm<<<NROW / 64, 192, 0, stream>>>(x, wtp, bih0, xpT);
    gru_fused<<<BSZ, 768, 0, stream>>>(xpT, whh0, bhh0, wih1, bih1, whh1, bhh1, hbuf);
    for (int l = 0; l < 2; l++) {
        sindy_mfma<<<NROW / 64, 512, 0, stream>>>(
            hbuf, cpk[l], w1pk[l], w2pk[l],
            ln1g + l * H, ln1b + l * H, b1 + l * FFD,
            b2 + l * H, ln2g + l * H, ln2b + l * H,
            out, l == 1);
    }
}

// Round 7
// 519.917 us; speedup vs baseline: 1.4877x; 1.0895x over previous
//
#include <hip/hip_runtime.h>
#include <hip/hip_bf16.h>
#include <math.h>

#define H 64
#define DM 128
#define GDIM 192      // 3*H
#define BSZ 32
#define SEQ 500
#define NROW (BSZ*SEQ)  // 16000
#define LIBN 2145
#define FFD 128
#define NKC2 75       // padded grouped-K chunks of 32 (2400 slots, 300 groups)
#define NGRP 300
#define CPK2 153600   // NKC2*4*64*8 shorts per layer

typedef __attribute__((ext_vector_type(8))) short short8;   // bf16x8 MFMA operand
typedef __attribute__((ext_vector_type(4))) float f32x4;    // MFMA accumulator
typedef __attribute__((ext_vector_type(2))) float f32x2;    // packed-math pair
typedef __attribute__((ext_vector_type(4))) unsigned u32x4;

__device__ __forceinline__ float sigf(float x) {
    return 1.0f / (1.0f + __expf(-x));
}
__device__ __forceinline__ float tanhfast(float x) {
    x = fminf(fmaxf(x, -15.0f), 15.0f);
    float t = __expf(-2.0f * x);
    return (1.0f - t) / (1.0f + t);
}
__device__ __forceinline__ short bf16r(float f) {   // fp32 -> bf16 rne
    unsigned u = __float_as_uint(f);
    unsigned r = (u + 0x7fffu + ((u >> 16) & 1u)) >> 16;
    return (short)r;
}
// packed dual-FMA: d.lo = a.lo*b.lo + c.lo, d.hi = a.hi*b.hi + c.hi (1 inst vs 2)
__device__ __forceinline__ f32x2 pkfma(f32x2 a, f32x2 b, f32x2 c) {
    f32x2 d;
    asm("v_pk_fma_f32 %0, %1, %2, %3" : "=v"(d) : "v"(a), "v"(b), "v"(c));
    return d;
}

// decode grouped-K group id -> (a, b): af[j] = z[a] * z[b + j], j = 0..7
__device__ __forceinline__ void grp_decode(int g, int& a, int& b) {
    if (g < 8) { a = 64; b = g * 8; }                 // linear: 1 * z[8g..8g+7]
    else if (g == 8 || g >= 297) { a = 64; b = 64; }  // const slot / padding
    else {
        int G = g - 9, acc = 0;
        a = 0; b = 0;
        for (int i2 = 0; i2 < 64; i2++) {
            int cnt = 8 - (i2 >> 3);                  // aligned 8-groups covering [i2,63]
            if (G < acc + cnt) { a = i2; b = ((i2 >> 3) + (G - acc)) * 8; break; }
            acc += cnt;
        }
    }
}

// ---------------- ONE fused pack kernel (was 7 launches) -----------------------------
// idx ranges: [0,24576) wih0->wtp; then per-layer blocks of 169984 = coef 153600 +
// w1 8192 + w2 8192, writing into bfa laid out [cpk0][cpk1][w1p0][w1p1][w2p0][w2p1].
__global__ void pack_all(const float* __restrict__ wih0,
                         const float* __restrict__ coeffs,
                         const float* __restrict__ w1,
                         const float* __restrict__ w2,
                         float* __restrict__ wtp,
                         short* __restrict__ bfa) {
    int idx = blockIdx.x * 256 + threadIdx.x;        // grid covers exactly 364544
    if (idx < GDIM * DM) {                           // ---- wih0 -> wtp ----
        int e  = idx & 3;
        int g  = (idx >> 2) % GDIM;
        int k4 = idx / (GDIM * 4);
        wtp[idx] = wih0[g * DM + k4 * 4 + e];
        return;
    }
    int r = idx - GDIM * DM;
    int l = r / (CPK2 + 2 * 8192);
    int q = r % (CPK2 + 2 * 8192);
    if (q < CPK2) {                                  // ---- coef (grouped-K) ----
        const float* coef = coeffs + (size_t)l * LIBN * H;
        int j = q & 7, lane = (q >> 3) & 63, nt = (q >> 9) & 3, kc = q >> 11;
        int grp = kc * 4 + (lane >> 4);
        int row = -1;
        if (grp < 8) row = 1 + grp * 8 + j;
        else if (grp == 8) row = (j == 0) ? 0 : -1;
        else if (grp < 297) {
            int a, b;
            grp_decode(grp, a, b);
            int jdx = b + j;
            if (jdx >= a) row = 65 + a * 64 - (a * (a - 1)) / 2 + (jdx - a);
        }
        int c = nt * 16 + (lane & 15);
        bfa[(size_t)l * CPK2 + q] = (row >= 0) ? bf16r(coef[(size_t)row * H + c]) : (short)0;
        return;
    }
    int q2 = q - CPK2;
    if (q2 < 8192) {                                 // ---- W1^T fragments ----
        const float* w1l = w1 + (size_t)l * FFD * H;
        int j = q2 & 7, lane = (q2 >> 3) & 63, nt = (q2 >> 9) & 7, kc = q2 >> 12;
        int k = kc * 32 + ((lane >> 4) << 3) + j;
        int n = nt * 16 + (lane & 15);
        bfa[(size_t)2 * CPK2 + l * 8192 + q2] = bf16r(w1l[(size_t)n * H + k]);
        return;
    }
    int q3 = q2 - 8192;                              // ---- W2^T fragments ----
    const float* w2l = w2 + (size_t)l * H * FFD;
    int j = q3 & 7, lane = (q3 >> 3) & 63, nt = (q3 >> 9) & 3, kc = q3 >> 11;
    int k = kc * 32 + ((lane >> 4) << 3) + j;
    int n = nt * 16 + (lane & 15);
    bfa[(size_t)2 * CPK2 + 2 * 8192 + l * 8192 + q3] = bf16r(w2l[(size_t)n * FFD + k]);
}

// ---------------- xp0 = x @ Wih0^T + bih0, stored in GRU chunk layout ----------------
__global__ __launch_bounds__(192, 2) void xp0_gemm(const float* __restrict__ x,
                                                   const float* __restrict__ wtp,
                                                   const float* __restrict__ bih0,
                                                   float* __restrict__ xpT) {
    __shared__ float xs[64][DM];
    int rb = blockIdx.x * 64;
    for (int idx = threadIdx.x; idx < 64 * 32; idx += 192) {
        int r = idx >> 5, k4 = idx & 31;
        ((f32x4*)xs[r])[k4] = ((const f32x4*)(x + (size_t)(rb + r) * DM))[k4];
    }
    __syncthreads();
    int g = threadIdx.x;
    float bias = bih0[g];
    float acc[64];
#pragma unroll
    for (int r = 0; r < 64; r++) acc[r] = bias;
    for (int k4 = 0; k4 < 32; k4++) {
        f32x4 w4 = ((const f32x4*)wtp)[k4 * GDIM + g];
#pragma unroll
        for (int r = 0; r < 64; r++) {
            f32x4 xv = ((f32x4*)xs[r])[k4];
            acc[r] += w4[0] * xv[0] + w4[1] * xv[1] + w4[2] * xv[2] + w4[3] * xv[3];
        }
    }
    for (int r = 0; r < 64; r++) {
        int row = rb + r;
        int bb = row / 500;
        int ss = row - bb * 500;
        xpT[(((size_t)bb * 125 + (ss >> 2)) * GDIM + g) * 4 + (ss & 3)] = acc[r];
    }
}

// ---------------- fused 2-layer GRU scan: R0 12-wave structure + pk_fma phase 1 ------
// Wave (m = wv%3, q = wv/3) computes K-chunk [16q,16q+16) of matvec m (m0: Whh0@h0,
// m1: Wih1@h0, m2: Whh1@h1); lane i owns rows {i,64+i,128+i}. Gate waves: wv0 = layer0,
// wv2 = layer1 (one step skewed). xp inputs read 2 chunks (8 steps) ahead into a
// 4-buffer register ring; h1 outputs buffered 4 steps in regs.
// NEW: phase-1 matvec uses v_pk_fma_f32 (48 FMA -> 24 pk_fma per wave-step) — phase 1
// is issue-bound (VALUBusy ~62% on active CUs; 12 waves x ~70 insts x 2cy / 4 SIMDs).
__global__ __launch_bounds__(768, 3) void gru_fused(const float* __restrict__ xpT,
                                                    const float* __restrict__ whh0,
                                                    const float* __restrict__ bhh0,
                                                    const float* __restrict__ wih1,
                                                    const float* __restrict__ bih1,
                                                    const float* __restrict__ whh1,
                                                    const float* __restrict__ bhh1,
                                                    float* __restrict__ hbuf) {
    int b = blockIdx.x;
    int tid = threadIdx.x;
    int wv = __builtin_amdgcn_readfirstlane(tid >> 6);
    int lane = tid & 63;
    int m = wv % 3;
    int q = wv / 3;
    int k0 = q * 16;

    __shared__ __align__(16) float h0s[H];
    __shared__ __align__(16) float h1s[H];
    __shared__ float part[3][4][GDIM];

    if (tid < H) { h0s[tid] = 0.0f; h1s[tid] = 0.0f; }

    const float* W = (m == 0) ? whh0 : (m == 1) ? wih1 : whh1;
    f32x2 wrp[8], wzp[8], wnp[8];                  // 48 weight VGPRs as f32x2 pairs
#pragma unroll
    for (int k4 = 0; k4 < 4; k4++) {
        f32x4 a = ((const f32x4*)(W + (size_t)lane * H + k0))[k4];
        f32x4 c = ((const f32x4*)(W + (size_t)(H + lane) * H + k0))[k4];
        f32x4 d = ((const f32x4*)(W + (size_t)(2 * H + lane) * H + k0))[k4];
        wrp[2*k4]   = __builtin_shufflevector(a, a, 0, 1);
        wrp[2*k4+1] = __builtin_shufflevector(a, a, 2, 3);
        wzp[2*k4]   = __builtin_shufflevector(c, c, 0, 1);
        wzp[2*k4+1] = __builtin_shufflevector(c, c, 2, 3);
        wnp[2*k4]   = __builtin_shufflevector(d, d, 0, 1);
        wnp[2*k4+1] = __builtin_shufflevector(d, d, 2, 3);
    }

    float b0r = 0, b0z = 0, b0n = 0;
    float b1ir = 0, b1iz = 0, b1in = 0, b1hr = 0, b1hz = 0, b1hn = 0;
    float hreg0 = 0.0f, hreg1 = 0.0f;
    float hb4[4] = {0.f, 0.f, 0.f, 0.f};
    f32x4 xc[4][3];
    const float* xpB = xpT + (size_t)b * 125 * GDIM * 4;

    if (wv == 0) {
        b0r = bhh0[lane]; b0z = bhh0[H + lane]; b0n = bhh0[2 * H + lane];
#pragma unroll
        for (int g3 = 0; g3 < 3; g3++) {
            xc[0][g3] = *(const f32x4*)(xpB + ((size_t)0 * GDIM + g3 * 64 + lane) * 4);
            xc[1][g3] = *(const f32x4*)(xpB + ((size_t)1 * GDIM + g3 * 64 + lane) * 4);
        }
    } else if (wv == 2) {
        b1ir = bih1[lane]; b1iz = bih1[H + lane]; b1in = bih1[2 * H + lane];
        b1hr = bhh1[lane]; b1hz = bhh1[H + lane]; b1hn = bhh1[2 * H + lane];
    }
    __syncthreads();

    auto loadch = [&](int c, int buf) {
        if (c < 125) {
#pragma unroll
            for (int g3 = 0; g3 < 3; g3++)
                xc[buf][g3] = *(const f32x4*)(xpB + ((size_t)c * GDIM + g3 * 64 + lane) * 4);
        }
    };

    auto step = [&](int s, int e, float xr, float xz, float xn) {
        // phase 1: partial matvec over K-chunk [k0, k0+16) with packed dual-FMA;
        // h reads are wave-uniform addresses -> LDS broadcast.
        const float* hv = (m == 2) ? h1s : h0s;
        f32x2 arp = {0.f, 0.f}, azp = {0.f, 0.f}, anp = {0.f, 0.f};
#pragma unroll
        for (int t4 = 0; t4 < 4; t4++) {
            f32x4 h4 = ((const f32x4*)(hv + k0))[t4];
            f32x2 hlo = __builtin_shufflevector(h4, h4, 0, 1);
            f32x2 hhi = __builtin_shufflevector(h4, h4, 2, 3);
            arp = pkfma(wrp[2*t4], hlo, arp);
            arp = pkfma(wrp[2*t4+1], hhi, arp);
            azp = pkfma(wzp[2*t4], hlo, azp);
            azp = pkfma(wzp[2*t4+1], hhi, azp);
            anp = pkfma(wnp[2*t4], hlo, anp);
            anp = pkfma(wnp[2*t4+1], hhi, anp);
        }
        part[m][q][lane] = arp[0] + arp[1];
        part[m][q][H + lane] = azp[0] + azp[1];
        part[m][q][2 * H + lane] = anp[0] + anp[1];
        __syncthreads();

        // phase 2: gates
        if (wv == 0) {
            if (s < SEQ) {
                float gr = b0r, gz = b0z, gn = b0n;
#pragma unroll
                for (int qq = 0; qq < 4; qq++) {
                    gr += part[0][qq][lane];
                    gz += part[0][qq][H + lane];
                    gn += part[0][qq][2 * H + lane];
                }
                float rg = sigf(xr + gr);
                float zg = sigf(xz + gz);
                float ng = tanhfast(xn + rg * gn);
                hreg0 = (1.0f - zg) * ng + zg * hreg0;
                h0s[lane] = hreg0;
            }
        } else if (wv == 2) {
            if (s >= 1) {
                float xr1 = b1ir, xz1 = b1iz, xn1 = b1in;
                float gr1 = b1hr, gz1 = b1hz, gn1 = b1hn;
#pragma unroll
                for (int qq = 0; qq < 4; qq++) {
                    xr1 += part[1][qq][lane];
                    xz1 += part[1][qq][H + lane];
                    xn1 += part[1][qq][2 * H + lane];
                    gr1 += part[2][qq][lane];
                    gz1 += part[2][qq][H + lane];
                    gn1 += part[2][qq][2 * H + lane];
                }
                float rg = sigf(xr1 + gr1);
                float zg = sigf(xz1 + gz1);
                float ng = tanhfast(xn1 + rg * gn1);
                hreg1 = (1.0f - zg) * ng + zg * hreg1;
                h1s[lane] = hreg1;
                hb4[(e + 3) & 3] = hreg1;                 // h1[s-1], (s-1)&3 == (e+3)&3
                if (e == 0) {                              // s in {4,8,...,500}: flush h1[s-4..s-1]
                    float* dst = hbuf + ((size_t)b * SEQ + (s - 4)) * H + lane;
#pragma unroll
                    for (int t = 0; t < 4; t++) dst[t * H] = hb4[t];
                }
            }
        }
        __syncthreads();
    };

    for (int scb = 0; scb < 31; scb++) {
#pragma unroll
        for (int sci = 0; sci < 4; sci++) {
            int sc = scb * 4 + sci;
            if (wv == 0 && (sci & 1) == 0) {
                loadch(sc + 2, (sci + 2) & 3);
                loadch(sc + 3, (sci + 3) & 3);
            }
            int s0 = sc * 4;
            step(s0 + 0, 0, xc[sci][0][0], xc[sci][1][0], xc[sci][2][0]);
            step(s0 + 1, 1, xc[sci][0][1], xc[sci][1][1], xc[sci][2][1]);
            step(s0 + 2, 2, xc[sci][0][2], xc[sci][1][2], xc[sci][2][2]);
            step(s0 + 3, 3, xc[sci][0][3], xc[sci][1][3], xc[sci][2][3]);
        }
    }
    {   // sc = 124 (buf 0, loaded at sc=122)
        step(496, 0, xc[0][0][0], xc[0][1][0], xc[0][2][0]);
        step(497, 1, xc[0][0][1], xc[0][1][1], xc[0][2][1]);
        step(498, 2, xc[0][0][2], xc[0][1][2], xc[0][2][2]);
        step(499, 3, xc[0][0][3], xc[0][1][3], xc[0][2][3]);
    }
    // tail s = 500: produces h1[499] and flushes h1[496..499]
    step(500, 0, 0.0f, 0.0f, 0.0f);
}

// ---------------- MFMA SINDy layer: grouped-K theta build (unchanged from R6) --------
__global__ __launch_bounds__(512) void sindy_mfma(float* __restrict__ hbuf,
                                                  const short* __restrict__ cpk,
                                                  const short* __restrict__ w1p,
                                                  const short* __restrict__ w2p,
                                                  const float* __restrict__ g1,
                                                  const float* __restrict__ b1n,
                                                  const float* __restrict__ bf1,
                                                  const float* __restrict__ bf2v,
                                                  const float* __restrict__ g2,
                                                  const float* __restrict__ b2n,
                                                  float* __restrict__ out,
                                                  int final_layer) {
    __shared__ float z[65 * 68];                   // row 64 = zero pad (safe b-reads)
    __shared__ float upd[64 * 68];
    __shared__ float ff[64 * 132];
    __shared__ unsigned kmap2[NGRP];               // per-group (a<<16)|b
    __shared__ float bfs1[FFD], bfs2[H], g1s[H], b1s[H], g2s[H], b2s[H];

    int tid = threadIdx.x;
    int wv = __builtin_amdgcn_readfirstlane(tid >> 6);
    int lane = tid & 63;
    int row0 = blockIdx.x * 64;

    for (int idx = tid; idx < 64 * 16; idx += 512) {
        int r = idx >> 4, c4 = idx & 15;
        *(f32x4*)&z[r * 68 + c4 * 4] = *(const f32x4*)&hbuf[(size_t)(row0 + r) * H + c4 * 4];
    }
    for (int idx = tid; idx < 64 * 17; idx += 512)
        *(f32x4*)&upd[idx * 4] = (f32x4){0.f, 0.f, 0.f, 0.f};
    if (tid < 64) {
        z[tid * 68 + 64] = 1.0f; z[tid * 68 + 65] = 0.0f;
        z[tid * 68 + 66] = 0.0f; z[tid * 68 + 67] = 0.0f;
    }
    if (tid < 68) z[64 * 68 + tid] = 0.0f;         // zero pad row
    if (tid < NGRP) {
        int a, b;
        grp_decode(tid, a, b);
        kmap2[tid] = ((unsigned)a << 16) | (unsigned)b;
    }
    if (tid < FFD) bfs1[tid] = bf1[tid];
    if (tid < H) {
        bfs2[tid] = bf2v[tid];
        g1s[tid] = g1[tid]; b1s[tid] = b1n[tid];
        g2s[tid] = g2[tid]; b2s[tid] = b2n[tid];
    }
    __syncthreads();

    int kj0 = ((lane >> 4) << 3);
    int m0 = (wv & 3) * 16;
    int m = m0 + (lane & 15);
    int rbase = m0 + ((lane >> 4) << 2);
    int cb16 = lane & 15;
    const float* zrow = &z[m * 68];

    // ---- phase 1: upd = theta @ coef (grouped-K, k-split 2-way) ----
    {
        int p = wv >> 2;
        f32x4 acc[4] = {{0,0,0,0},{0,0,0,0},{0,0,0,0},{0,0,0,0}};
        for (int kc = p; kc < NKC2; kc += 2) {
            unsigned ab = kmap2[kc * 4 + (lane >> 4)];
            float za = zrow[ab >> 16];
            const float* zb = &zrow[ab & 0xffffu];
            f32x4 z0 = *(const f32x4*)zb;
            f32x4 z1 = *(const f32x4*)(zb + 4);
            short8 af;
            af[0] = bf16r(za * z0[0]);
            af[1] = bf16r(za * z0[1]);
            af[2] = bf16r(za * z0[2]);
            af[3] = bf16r(za * z0[3]);
            af[4] = bf16r(za * z1[0]);
            af[5] = bf16r(za * z1[1]);
            af[6] = bf16r(za * z1[2]);
            af[7] = bf16r(za * z1[3]);
            const short* cb = cpk + ((size_t)(kc * 4) * 64 + lane) * 8;
#pragma unroll
            for (int nt = 0; nt < 4; nt++) {
                short8 bf = *(const short8*)(cb + (size_t)nt * 512);
                acc[nt] = __builtin_amdgcn_mfma_f32_16x16x32_bf16(af, bf, acc[nt], 0, 0, 0);
            }
        }
#pragma unroll
        for (int nt = 0; nt < 4; nt++)
#pragma unroll
            for (int r = 0; r < 4; r++)
                atomicAdd(&upd[(rbase + r) * 68 + nt * 16 + cb16], acc[nt][r]);
    }
    __syncthreads();

    // ---- phase 2: LN1 (wave 0) -> z ----
    if (wv == 0) {
        float v[64];
        float s1 = 0.0f;
#pragma unroll
        for (int c = 0; c < 64; c++) { v[c] = z[lane * 68 + c] + upd[lane * 68 + c]; s1 += v[c]; }
        float mn = s1 * (1.0f / 64.0f);
        float s2 = 0.0f;
#pragma unroll
        for (int c = 0; c < 64; c++) { float d = v[c] - mn; s2 += d * d; }
        float rstd = 1.0f / sqrtf(s2 * (1.0f / 64.0f) + 1e-5f);
#pragma unroll
        for (int c = 0; c < 64; c++)
            z[lane * 68 + c] = (v[c] - mn) * rstd * g1s[c] + b1s[c];
    }
    __syncthreads();

    // ---- phase 3: ff = gelu(LN1 @ W1^T + b1) ----
    {
        int nq = wv >> 2;
        f32x4 acc[4] = {{0,0,0,0},{0,0,0,0},{0,0,0,0},{0,0,0,0}};
#pragma unroll
        for (int kc = 0; kc < 2; kc++) {
            f32x4 za = *(const f32x4*)&z[m * 68 + kc * 32 + kj0];
            f32x4 zb = *(const f32x4*)&z[m * 68 + kc * 32 + kj0 + 4];
            short8 af;
            af[0] = bf16r(za[0]); af[1] = bf16r(za[1]); af[2] = bf16r(za[2]); af[3] = bf16r(za[3]);
            af[4] = bf16r(zb[0]); af[5] = bf16r(zb[1]); af[6] = bf16r(zb[2]); af[7] = bf16r(zb[3]);
#pragma unroll
            for (int t = 0; t < 4; t++) {
                int nt = nq * 4 + t;
                short8 bf = *(const short8*)(w1p + ((size_t)(kc * 8 + nt) * 64 + lane) * 8);
                acc[t] = __builtin_amdgcn_mfma_f32_16x16x32_bf16(af, bf, acc[t], 0, 0, 0);
            }
        }
#pragma unroll
        for (int t = 0; t < 4; t++) {
            int col = (nq * 4 + t) * 16 + cb16;
#pragma unroll
            for (int r = 0; r < 4; r++) {
                float v = acc[t][r] + bfs1[col];
                ff[(rbase + r) * 132 + col] = 0.5f * v * (1.0f + erff(v * 0.70710678118654752f));
            }
        }
    }
    __syncthreads();

    // ---- phase 5: upd = ff @ W2^T + b2 ----
    {
        int nh = wv >> 2;
        f32x4 acc[2] = {{0,0,0,0},{0,0,0,0}};
        const float* frow = &ff[m * 132];
#pragma unroll
        for (int kc = 0; kc < 4; kc++) {
            f32x4 fa = *(const f32x4*)&frow[kc * 32 + kj0];
            f32x4 fb = *(const f32x4*)&frow[kc * 32 + kj0 + 4];
            short8 af;
            af[0] = bf16r(fa[0]); af[1] = bf16r(fa[1]); af[2] = bf16r(fa[2]); af[3] = bf16r(fa[3]);
            af[4] = bf16r(fb[0]); af[5] = bf16r(fb[1]); af[6] = bf16r(fb[2]); af[7] = bf16r(fb[3]);
#pragma unroll
            for (int t = 0; t < 2; t++) {
                int nt = nh * 2 + t;
                short8 bf = *(const short8*)(w2p + ((size_t)(kc * 4 + nt) * 64 + lane) * 8);
                acc[t] = __builtin_amdgcn_mfma_f32_16x16x32_bf16(af, bf, acc[t], 0, 0, 0);
            }
        }
#pragma unroll
        for (int t = 0; t < 2; t++) {
            int col = (nh * 2 + t) * 16 + cb16;
#pragma unroll
            for (int r = 0; r < 4; r++)
                upd[(rbase + r) * 68 + col] = acc[t][r] + bfs2[col];
        }
    }
    __syncthreads();

    // ---- phase 6: LN2 + write (wave 0) ----
    if (wv == 0) {
        float v[64];
        float s1 = 0.0f;
#pragma unroll
        for (int c = 0; c < 64; c++) { v[c] = z[lane * 68 + c] + upd[lane * 68 + c]; s1 += v[c]; }
        float mn = s1 * (1.0f / 64.0f);
        float s2 = 0.0f;
#pragma unroll
        for (int c = 0; c < 64; c++) { float d = v[c] - mn; s2 += d * d; }
        float rstd = 1.0f / sqrtf(s2 * (1.0f / 64.0f) + 1e-5f);
        int row = row0 + lane;
#pragma unroll
        for (int c = 0; c < 64; c++) {
            float res = (v[c] - mn) * rstd * g2s[c] + b2s[c];
            if (!final_layer) {
                hbuf[(size_t)row * H + c] = res;
            } else {
                out[(size_t)row * H + c] = res;
                if (row % SEQ == SEQ - 1)
                    out[(size_t)NROW * H + (row / SEQ) * H + c] = res;
            }
        }
    }
}

extern "C" void kernel_launch(void* const* d_in, const int* in_sizes, int n_in,
                              void* d_out, int out_size, void* d_ws, size_t ws_size,
                              hipStream_t stream) {
    const float* x    = (const float*)d_in[0];
    const float* wih0 = (const float*)d_in[1];
    const float* whh0 = (const float*)d_in[2];
    const float* bih0 = (const float*)d_in[3];
    const float* bhh0 = (const float*)d_in[4];
    const float* wih1 = (const float*)d_in[5];
    const float* whh1 = (const float*)d_in[6];
    const float* bih1 = (const float*)d_in[7];
    const float* bhh1 = (const float*)d_in[8];
    const float* coeffs = (const float*)d_in[9];
    const float* ln1g = (const float*)d_in[10];
    const float* ln1b = (const float*)d_in[11];
    const float* w1   = (const float*)d_in[12];
    const float* b1   = (const float*)d_in[13];
    const float* w2   = (const float*)d_in[14];
    const float* b2   = (const float*)d_in[15];
    const float* ln2g = (const float*)d_in[16];
    const float* ln2b = (const float*)d_in[17];

    float* out = (float*)d_out;
    float* ws  = (float*)d_ws;
    float* xpT = ws;                               // 16000*192 = 3,072,000 floats
    float* wtp = ws + (size_t)NROW * GDIM;         // 24,576 floats
    short* bfa = (short*)(wtp + GDIM * DM);        // bf16 fragment area
    short* cpk[2] = { bfa, bfa + CPK2 };
    short* w1pk[2] = { bfa + 2 * CPK2, bfa + 2 * CPK2 + 8192 };
    short* w2pk[2] = { bfa + 2 * CPK2 + 2 * 8192, bfa + 2 * CPK2 + 3 * 8192 };
    float* hbuf = out;                             // reuse first 1,024,000 floats of d_out

    // one fused pack launch: 24576 + 2*(153600+8192+8192) = 364544 = 1424*256
    pack_all<<<1424, 256, 0, stream>>>(wih0, coeffs, w1, w2, wtp, bfa);
    xp0_gemm<<<NROW / 64, 192, 0, stream>>>(x, wtp, bih0, xpT);
    gru_fused<<<BSZ, 768, 0, stream>>>(xpT, whh0, bhh0, wih1, bih1, whh1, bhh1, hbuf);
    for (int l = 0; l < 2; l++) {
        sindy_mfma<<<NROW / 64, 512, 0, stream>>>(
            hbuf, cpk[l], w1pk[l], w2pk[l],
            ln1g + l * H, ln1b + l * H, b1 + l * FFD,
            b2 + l * H, ln2g + l * H, ln2b + l * H,
            out, l == 1);
    }
}

// Round 8
// 510.228 us; speedup vs baseline: 1.5159x; 1.0190x over previous
//
#include <hip/hip_runtime.h>
#include <hip/hip_bf16.h>
#include <math.h>

#define H 64
#define DM 128
#define GDIM 192      // 3*H
#define BSZ 32
#define SEQ 500
#define NROW (BSZ*SEQ)  // 16000
#define LIBN 2145
#define FFD 128
#define NKC2 75       // padded grouped-K chunks of 32 (2400 slots, 300 groups)
#define NGRP 300
#define CPK2 153600   // NKC2*4*64*8 shorts per layer

typedef __attribute__((ext_vector_type(8))) short short8;   // bf16x8 MFMA operand
typedef __attribute__((ext_vector_type(4))) float f32x4;    // MFMA accumulator
typedef __attribute__((ext_vector_type(2))) float f32x2;    // packed-math pair
typedef __attribute__((ext_vector_type(4))) unsigned u32x4;

__device__ __forceinline__ float sigf(float x) {
    return 1.0f / (1.0f + __expf(-x));
}
__device__ __forceinline__ float tanhfast(float x) {
    x = fminf(fmaxf(x, -15.0f), 15.0f);
    float t = __expf(-2.0f * x);
    return (1.0f - t) / (1.0f + t);
}
__device__ __forceinline__ short bf16r(float f) {   // fp32 -> bf16 rne
    unsigned u = __float_as_uint(f);
    unsigned r = (u + 0x7fffu + ((u >> 16) & 1u)) >> 16;
    return (short)r;
}
// packed dual-FMA: d.lo = a.lo*b.lo + c.lo, d.hi = a.hi*b.hi + c.hi (1 inst vs 2)
__device__ __forceinline__ f32x2 pkfma(f32x2 a, f32x2 b, f32x2 c) {
    f32x2 d;
    asm("v_pk_fma_f32 %0, %1, %2, %3" : "=v"(d) : "v"(a), "v"(b), "v"(c));
    return d;
}

// decode grouped-K group id -> (a, b): af[j] = z[a] * z[b + j], j = 0..7
__device__ __forceinline__ void grp_decode(int g, int& a, int& b) {
    if (g < 8) { a = 64; b = g * 8; }                 // linear: 1 * z[8g..8g+7]
    else if (g == 8 || g >= 297) { a = 64; b = 64; }  // const slot / padding
    else {
        int G = g - 9, acc = 0;
        a = 0; b = 0;
        for (int i2 = 0; i2 < 64; i2++) {
            int cnt = 8 - (i2 >> 3);                  // aligned 8-groups covering [i2,63]
            if (G < acc + cnt) { a = i2; b = ((i2 >> 3) + (G - acc)) * 8; break; }
            acc += cnt;
        }
    }
}

// ---------------- ONE fused pack kernel -----------------------------------------------
__global__ void pack_all(const float* __restrict__ wih0,
                         const float* __restrict__ coeffs,
                         const float* __restrict__ w1,
                         const float* __restrict__ w2,
                         float* __restrict__ wtp,
                         short* __restrict__ bfa) {
    int idx = blockIdx.x * 256 + threadIdx.x;        // grid covers exactly 364544
    if (idx < GDIM * DM) {                           // ---- wih0 -> wtp ----
        int e  = idx & 3;
        int g  = (idx >> 2) % GDIM;
        int k4 = idx / (GDIM * 4);
        wtp[idx] = wih0[g * DM + k4 * 4 + e];
        return;
    }
    int r = idx - GDIM * DM;
    int l = r / (CPK2 + 2 * 8192);
    int q = r % (CPK2 + 2 * 8192);
    if (q < CPK2) {                                  // ---- coef (grouped-K) ----
        const float* coef = coeffs + (size_t)l * LIBN * H;
        int j = q & 7, lane = (q >> 3) & 63, nt = (q >> 9) & 3, kc = q >> 11;
        int grp = kc * 4 + (lane >> 4);
        int row = -1;
        if (grp < 8) row = 1 + grp * 8 + j;
        else if (grp == 8) row = (j == 0) ? 0 : -1;
        else if (grp < 297) {
            int a, b;
            grp_decode(grp, a, b);
            int jdx = b + j;
            if (jdx >= a) row = 65 + a * 64 - (a * (a - 1)) / 2 + (jdx - a);
        }
        int c = nt * 16 + (lane & 15);
        bfa[(size_t)l * CPK2 + q] = (row >= 0) ? bf16r(coef[(size_t)row * H + c]) : (short)0;
        return;
    }
    int q2 = q - CPK2;
    if (q2 < 8192) {                                 // ---- W1^T fragments ----
        const float* w1l = w1 + (size_t)l * FFD * H;
        int j = q2 & 7, lane = (q2 >> 3) & 63, nt = (q2 >> 9) & 7, kc = q2 >> 12;
        int k = kc * 32 + ((lane >> 4) << 3) + j;
        int n = nt * 16 + (lane & 15);
        bfa[(size_t)2 * CPK2 + l * 8192 + q2] = bf16r(w1l[(size_t)n * H + k]);
        return;
    }
    int q3 = q2 - 8192;                              // ---- W2^T fragments ----
    const float* w2l = w2 + (size_t)l * H * FFD;
    int j = q3 & 7, lane = (q3 >> 3) & 63, nt = (q3 >> 9) & 3, kc = q3 >> 11;
    int k = kc * 32 + ((lane >> 4) << 3) + j;
    int n = nt * 16 + (lane & 15);
    bfa[(size_t)2 * CPK2 + 2 * 8192 + l * 8192 + q3] = bf16r(w2l[(size_t)n * FFD + k]);
}

// ---------------- xp0 = x @ Wih0^T + bih0, stored in GRU chunk layout ----------------
__global__ __launch_bounds__(192, 2) void xp0_gemm(const float* __restrict__ x,
                                                   const float* __restrict__ wtp,
                                                   const float* __restrict__ bih0,
                                                   float* __restrict__ xpT) {
    __shared__ float xs[64][DM];
    int rb = blockIdx.x * 64;
    for (int idx = threadIdx.x; idx < 64 * 32; idx += 192) {
        int r = idx >> 5, k4 = idx & 31;
        ((f32x4*)xs[r])[k4] = ((const f32x4*)(x + (size_t)(rb + r) * DM))[k4];
    }
    __syncthreads();
    int g = threadIdx.x;
    float bias = bih0[g];
    float acc[64];
#pragma unroll
    for (int r = 0; r < 64; r++) acc[r] = bias;
    for (int k4 = 0; k4 < 32; k4++) {
        f32x4 w4 = ((const f32x4*)wtp)[k4 * GDIM + g];
#pragma unroll
        for (int r = 0; r < 64; r++) {
            f32x4 xv = ((f32x4*)xs[r])[k4];
            acc[r] += w4[0] * xv[0] + w4[1] * xv[1] + w4[2] * xv[2] + w4[3] * xv[3];
        }
    }
    for (int r = 0; r < 64; r++) {
        int row = rb + r;
        int bb = row / 500;
        int ss = row - bb * 500;
        xpT[(((size_t)bb * 125 + (ss >> 2)) * GDIM + g) * 4 + (ss & 3)] = acc[r];
    }
}

// ---------------- fused 2-layer GRU scan: R7 12-wave + pk_fma (276 µs, FROZEN) -------
__global__ __launch_bounds__(768, 3) void gru_fused(const float* __restrict__ xpT,
                                                    const float* __restrict__ whh0,
                                                    const float* __restrict__ bhh0,
                                                    const float* __restrict__ wih1,
                                                    const float* __restrict__ bih1,
                                                    const float* __restrict__ whh1,
                                                    const float* __restrict__ bhh1,
                                                    float* __restrict__ hbuf) {
    int b = blockIdx.x;
    int tid = threadIdx.x;
    int wv = __builtin_amdgcn_readfirstlane(tid >> 6);
    int lane = tid & 63;
    int m = wv % 3;
    int q = wv / 3;
    int k0 = q * 16;

    __shared__ __align__(16) float h0s[H];
    __shared__ __align__(16) float h1s[H];
    __shared__ float part[3][4][GDIM];

    if (tid < H) { h0s[tid] = 0.0f; h1s[tid] = 0.0f; }

    const float* W = (m == 0) ? whh0 : (m == 1) ? wih1 : whh1;
    f32x2 wrp[8], wzp[8], wnp[8];                  // 48 weight VGPRs as f32x2 pairs
#pragma unroll
    for (int k4 = 0; k4 < 4; k4++) {
        f32x4 a = ((const f32x4*)(W + (size_t)lane * H + k0))[k4];
        f32x4 c = ((const f32x4*)(W + (size_t)(H + lane) * H + k0))[k4];
        f32x4 d = ((const f32x4*)(W + (size_t)(2 * H + lane) * H + k0))[k4];
        wrp[2*k4]   = __builtin_shufflevector(a, a, 0, 1);
        wrp[2*k4+1] = __builtin_shufflevector(a, a, 2, 3);
        wzp[2*k4]   = __builtin_shufflevector(c, c, 0, 1);
        wzp[2*k4+1] = __builtin_shufflevector(c, c, 2, 3);
        wnp[2*k4]   = __builtin_shufflevector(d, d, 0, 1);
        wnp[2*k4+1] = __builtin_shufflevector(d, d, 2, 3);
    }

    float b0r = 0, b0z = 0, b0n = 0;
    float b1ir = 0, b1iz = 0, b1in = 0, b1hr = 0, b1hz = 0, b1hn = 0;
    float hreg0 = 0.0f, hreg1 = 0.0f;
    float hb4[4] = {0.f, 0.f, 0.f, 0.f};
    f32x4 xc[4][3];
    const float* xpB = xpT + (size_t)b * 125 * GDIM * 4;

    if (wv == 0) {
        b0r = bhh0[lane]; b0z = bhh0[H + lane]; b0n = bhh0[2 * H + lane];
#pragma unroll
        for (int g3 = 0; g3 < 3; g3++) {
            xc[0][g3] = *(const f32x4*)(xpB + ((size_t)0 * GDIM + g3 * 64 + lane) * 4);
            xc[1][g3] = *(const f32x4*)(xpB + ((size_t)1 * GDIM + g3 * 64 + lane) * 4);
        }
    } else if (wv == 2) {
        b1ir = bih1[lane]; b1iz = bih1[H + lane]; b1in = bih1[2 * H + lane];
        b1hr = bhh1[lane]; b1hz = bhh1[H + lane]; b1hn = bhh1[2 * H + lane];
    }
    __syncthreads();

    auto loadch = [&](int c, int buf) {
        if (c < 125) {
#pragma unroll
            for (int g3 = 0; g3 < 3; g3++)
                xc[buf][g3] = *(const f32x4*)(xpB + ((size_t)c * GDIM + g3 * 64 + lane) * 4);
        }
    };

    auto step = [&](int s, int e, float xr, float xz, float xn) {
        const float* hv = (m == 2) ? h1s : h0s;
        f32x2 arp = {0.f, 0.f}, azp = {0.f, 0.f}, anp = {0.f, 0.f};
#pragma unroll
        for (int t4 = 0; t4 < 4; t4++) {
            f32x4 h4 = ((const f32x4*)(hv + k0))[t4];
            f32x2 hlo = __builtin_shufflevector(h4, h4, 0, 1);
            f32x2 hhi = __builtin_shufflevector(h4, h4, 2, 3);
            arp = pkfma(wrp[2*t4], hlo, arp);
            arp = pkfma(wrp[2*t4+1], hhi, arp);
            azp = pkfma(wzp[2*t4], hlo, azp);
            azp = pkfma(wzp[2*t4+1], hhi, azp);
            anp = pkfma(wnp[2*t4], hlo, anp);
            anp = pkfma(wnp[2*t4+1], hhi, anp);
        }
        part[m][q][lane] = arp[0] + arp[1];
        part[m][q][H + lane] = azp[0] + azp[1];
        part[m][q][2 * H + lane] = anp[0] + anp[1];
        __syncthreads();

        if (wv == 0) {
            if (s < SEQ) {
                float gr = b0r, gz = b0z, gn = b0n;
#pragma unroll
                for (int qq = 0; qq < 4; qq++) {
                    gr += part[0][qq][lane];
                    gz += part[0][qq][H + lane];
                    gn += part[0][qq][2 * H + lane];
                }
                float rg = sigf(xr + gr);
                float zg = sigf(xz + gz);
                float ng = tanhfast(xn + rg * gn);
                hreg0 = (1.0f - zg) * ng + zg * hreg0;
                h0s[lane] = hreg0;
            }
        } else if (wv == 2) {
            if (s >= 1) {
                float xr1 = b1ir, xz1 = b1iz, xn1 = b1in;
                float gr1 = b1hr, gz1 = b1hz, gn1 = b1hn;
#pragma unroll
                for (int qq = 0; qq < 4; qq++) {
                    xr1 += part[1][qq][lane];
                    xz1 += part[1][qq][H + lane];
                    xn1 += part[1][qq][2 * H + lane];
                    gr1 += part[2][qq][lane];
                    gz1 += part[2][qq][H + lane];
                    gn1 += part[2][qq][2 * H + lane];
                }
                float rg = sigf(xr1 + gr1);
                float zg = sigf(xz1 + gz1);
                float ng = tanhfast(xn1 + rg * gn1);
                hreg1 = (1.0f - zg) * ng + zg * hreg1;
                h1s[lane] = hreg1;
                hb4[(e + 3) & 3] = hreg1;                 // h1[s-1], (s-1)&3 == (e+3)&3
                if (e == 0) {                              // s in {4,8,...,500}: flush h1[s-4..s-1]
                    float* dst = hbuf + ((size_t)b * SEQ + (s - 4)) * H + lane;
#pragma unroll
                    for (int t = 0; t < 4; t++) dst[t * H] = hb4[t];
                }
            }
        }
        __syncthreads();
    };

    for (int scb = 0; scb < 31; scb++) {
#pragma unroll
        for (int sci = 0; sci < 4; sci++) {
            int sc = scb * 4 + sci;
            if (wv == 0 && (sci & 1) == 0) {
                loadch(sc + 2, (sci + 2) & 3);
                loadch(sc + 3, (sci + 3) & 3);
            }
            int s0 = sc * 4;
            step(s0 + 0, 0, xc[sci][0][0], xc[sci][1][0], xc[sci][2][0]);
            step(s0 + 1, 1, xc[sci][0][1], xc[sci][1][1], xc[sci][2][1]);
            step(s0 + 2, 2, xc[sci][0][2], xc[sci][1][2], xc[sci][2][2]);
            step(s0 + 3, 3, xc[sci][0][3], xc[sci][1][3], xc[sci][2][3]);
        }
    }
    {   // sc = 124 (buf 0, loaded at sc=122)
        step(496, 0, xc[0][0][0], xc[0][1][0], xc[0][2][0]);
        step(497, 1, xc[0][0][1], xc[0][1][1], xc[0][2][1]);
        step(498, 2, xc[0][0][2], xc[0][1][2], xc[0][2][2]);
        step(499, 3, xc[0][0][3], xc[0][1][3], xc[0][2][3]);
    }
    // tail s = 500: produces h1[499] and flushes h1[496..499]
    step(500, 0, 0.0f, 0.0f, 0.0f);
}

// ---------------- FUSED 2-layer SINDy kernel + parallel LN ---------------------------
// Both layers are row-local -> one launch; z stays in LDS between layers (saves a
// 4MB write + 4MB read + 1 launch). LN1/LN2 now use all 512 threads (8 threads/row,
// 8-lane shfl_xor reduce) instead of wave-0-serial.
__global__ __launch_bounds__(512) void sindy_fused(const float* __restrict__ hbuf_in,
                                                   const short* __restrict__ bfa,
                                                   const float* __restrict__ ln1g,
                                                   const float* __restrict__ ln1b,
                                                   const float* __restrict__ b1g,
                                                   const float* __restrict__ b2g,
                                                   const float* __restrict__ ln2g,
                                                   const float* __restrict__ ln2b,
                                                   float* __restrict__ out) {
    __shared__ float z[65 * 68];                   // row 64 = zero pad (safe b-reads)
    __shared__ float upd[64 * 68];
    __shared__ float ff[64 * 132];
    __shared__ unsigned kmap2[NGRP];
    __shared__ float bfs1[2][FFD], bfs2[2][H];
    __shared__ float g1s[2][H], b1s[2][H], g2s[2][H], b2s[2][H];

    int tid = threadIdx.x;
    int wv = __builtin_amdgcn_readfirstlane(tid >> 6);
    int lane = tid & 63;
    int row0 = blockIdx.x * 64;

    for (int idx = tid; idx < 64 * 16; idx += 512) {
        int r = idx >> 4, c4 = idx & 15;
        *(f32x4*)&z[r * 68 + c4 * 4] = *(const f32x4*)&hbuf_in[(size_t)(row0 + r) * H + c4 * 4];
    }
    for (int idx = tid; idx < 64 * 17; idx += 512)
        *(f32x4*)&upd[idx * 4] = (f32x4){0.f, 0.f, 0.f, 0.f};
    if (tid < 64) {
        z[tid * 68 + 64] = 1.0f; z[tid * 68 + 65] = 0.0f;
        z[tid * 68 + 66] = 0.0f; z[tid * 68 + 67] = 0.0f;
    }
    if (tid < 68) z[64 * 68 + tid] = 0.0f;         // zero pad row
    if (tid < NGRP) {
        int a, b;
        grp_decode(tid, a, b);
        kmap2[tid] = ((unsigned)a << 16) | (unsigned)b;
    }
    if (tid < FFD) { bfs1[0][tid] = b1g[tid]; bfs1[1][tid] = b1g[FFD + tid]; }
    if (tid < H) {
        bfs2[0][tid] = b2g[tid];      bfs2[1][tid] = b2g[H + tid];
        g1s[0][tid] = ln1g[tid];      g1s[1][tid] = ln1g[H + tid];
        b1s[0][tid] = ln1b[tid];      b1s[1][tid] = ln1b[H + tid];
        g2s[0][tid] = ln2g[tid];      g2s[1][tid] = ln2g[H + tid];
        b2s[0][tid] = ln2b[tid];      b2s[1][tid] = ln2b[H + tid];
    }
    __syncthreads();

    int kj0 = ((lane >> 4) << 3);
    int m0 = (wv & 3) * 16;
    int m = m0 + (lane & 15);
    int rbase = m0 + ((lane >> 4) << 2);
    int cb16 = lane & 15;
    const float* zrow = &z[m * 68];
    int lrow = tid >> 3;                           // parallel-LN: row, 8 threads/row
    int lk = (tid & 7) * 8;                        // this thread's 8-col slice

#pragma unroll
    for (int l = 0; l < 2; l++) {
        const short* cpk = bfa + (size_t)l * CPK2;
        const short* w1p = bfa + (size_t)2 * CPK2 + l * 8192;
        const short* w2p = bfa + (size_t)2 * CPK2 + 2 * 8192 + l * 8192;

        // ---- phase 1: upd = theta @ coef (grouped-K, k-split 2-way) ----
        {
            int p = wv >> 2;
            f32x4 acc[4] = {{0,0,0,0},{0,0,0,0},{0,0,0,0},{0,0,0,0}};
            for (int kc = p; kc < NKC2; kc += 2) {
                unsigned ab = kmap2[kc * 4 + (lane >> 4)];
                float za = zrow[ab >> 16];
                const float* zb = &zrow[ab & 0xffffu];
                f32x4 z0 = *(const f32x4*)zb;
                f32x4 z1 = *(const f32x4*)(zb + 4);
                short8 af;
                af[0] = bf16r(za * z0[0]);
                af[1] = bf16r(za * z0[1]);
                af[2] = bf16r(za * z0[2]);
                af[3] = bf16r(za * z0[3]);
                af[4] = bf16r(za * z1[0]);
                af[5] = bf16r(za * z1[1]);
                af[6] = bf16r(za * z1[2]);
                af[7] = bf16r(za * z1[3]);
                const short* cb = cpk + ((size_t)(kc * 4) * 64 + lane) * 8;
#pragma unroll
                for (int nt = 0; nt < 4; nt++) {
                    short8 bf = *(const short8*)(cb + (size_t)nt * 512);
                    acc[nt] = __builtin_amdgcn_mfma_f32_16x16x32_bf16(af, bf, acc[nt], 0, 0, 0);
                }
            }
#pragma unroll
            for (int nt = 0; nt < 4; nt++)
#pragma unroll
                for (int r = 0; r < 4; r++)
                    atomicAdd(&upd[(rbase + r) * 68 + nt * 16 + cb16], acc[nt][r]);
        }
        __syncthreads();

        // ---- LN1 (all 512 threads, 8/row) -> z ----
        {
            float v[8];
            float s1 = 0.0f;
#pragma unroll
            for (int i = 0; i < 8; i++) {
                v[i] = z[lrow * 68 + lk + i] + upd[lrow * 68 + lk + i];
                s1 += v[i];
            }
            s1 += __shfl_xor(s1, 1); s1 += __shfl_xor(s1, 2); s1 += __shfl_xor(s1, 4);
            float mn = s1 * (1.0f / 64.0f);
            float s2 = 0.0f;
#pragma unroll
            for (int i = 0; i < 8; i++) { float d = v[i] - mn; s2 += d * d; }
            s2 += __shfl_xor(s2, 1); s2 += __shfl_xor(s2, 2); s2 += __shfl_xor(s2, 4);
            float rstd = 1.0f / sqrtf(s2 * (1.0f / 64.0f) + 1e-5f);
#pragma unroll
            for (int i = 0; i < 8; i++)
                z[lrow * 68 + lk + i] = (v[i] - mn) * rstd * g1s[l][lk + i] + b1s[l][lk + i];
        }
        __syncthreads();

        // ---- phase 3: ff = gelu(LN1 @ W1^T + b1) ----
        {
            int nq = wv >> 2;
            f32x4 acc[4] = {{0,0,0,0},{0,0,0,0},{0,0,0,0},{0,0,0,0}};
#pragma unroll
            for (int kc = 0; kc < 2; kc++) {
                f32x4 za = *(const f32x4*)&z[m * 68 + kc * 32 + kj0];
                f32x4 zb = *(const f32x4*)&z[m * 68 + kc * 32 + kj0 + 4];
                short8 af;
                af[0] = bf16r(za[0]); af[1] = bf16r(za[1]); af[2] = bf16r(za[2]); af[3] = bf16r(za[3]);
                af[4] = bf16r(zb[0]); af[5] = bf16r(zb[1]); af[6] = bf16r(zb[2]); af[7] = bf16r(zb[3]);
#pragma unroll
                for (int t = 0; t < 4; t++) {
                    int nt = nq * 4 + t;
                    short8 bf = *(const short8*)(w1p + ((size_t)(kc * 8 + nt) * 64 + lane) * 8);
                    acc[t] = __builtin_amdgcn_mfma_f32_16x16x32_bf16(af, bf, acc[t], 0, 0, 0);
                }
            }
#pragma unroll
            for (int t = 0; t < 4; t++) {
                int col = (nq * 4 + t) * 16 + cb16;
#pragma unroll
                for (int r = 0; r < 4; r++) {
                    float v = acc[t][r] + bfs1[l][col];
                    ff[(rbase + r) * 132 + col] = 0.5f * v * (1.0f + erff(v * 0.70710678118654752f));
                }
            }
        }
        __syncthreads();

        // ---- phase 5: upd = ff @ W2^T + b2 (plain stores, full overwrite) ----
        {
            int nh = wv >> 2;
            f32x4 acc[2] = {{0,0,0,0},{0,0,0,0}};
            const float* frow = &ff[m * 132];
#pragma unroll
            for (int kc = 0; kc < 4; kc++) {
                f32x4 fa = *(const f32x4*)&frow[kc * 32 + kj0];
                f32x4 fb = *(const f32x4*)&frow[kc * 32 + kj0 + 4];
                short8 af;
                af[0] = bf16r(fa[0]); af[1] = bf16r(fa[1]); af[2] = bf16r(fa[2]); af[3] = bf16r(fa[3]);
                af[4] = bf16r(fb[0]); af[5] = bf16r(fb[1]); af[6] = bf16r(fb[2]); af[7] = bf16r(fb[3]);
#pragma unroll
                for (int t = 0; t < 2; t++) {
                    int nt = nh * 2 + t;
                    short8 bf = *(const short8*)(w2p + ((size_t)(kc * 4 + nt) * 64 + lane) * 8);
                    acc[t] = __builtin_amdgcn_mfma_f32_16x16x32_bf16(af, bf, acc[t], 0, 0, 0);
                }
            }
#pragma unroll
            for (int t = 0; t < 2; t++) {
                int col = (nh * 2 + t) * 16 + cb16;
#pragma unroll
                for (int r = 0; r < 4; r++)
                    upd[(rbase + r) * 68 + col] = acc[t][r] + bfs2[l][col];
            }
        }
        __syncthreads();

        // ---- LN2 (all 512 threads): l=0 -> z (stay in LDS); l=1 -> out ----
        {
            float v[8];
            float s1 = 0.0f;
#pragma unroll
            for (int i = 0; i < 8; i++) {
                v[i] = z[lrow * 68 + lk + i] + upd[lrow * 68 + lk + i];
                s1 += v[i];
            }
            s1 += __shfl_xor(s1, 1); s1 += __shfl_xor(s1, 2); s1 += __shfl_xor(s1, 4);
            float mn = s1 * (1.0f / 64.0f);
            float s2 = 0.0f;
#pragma unroll
            for (int i = 0; i < 8; i++) { float d = v[i] - mn; s2 += d * d; }
            s2 += __shfl_xor(s2, 1); s2 += __shfl_xor(s2, 2); s2 += __shfl_xor(s2, 4);
            float rstd = 1.0f / sqrtf(s2 * (1.0f / 64.0f) + 1e-5f);
            if (l == 0) {
#pragma unroll
                for (int i = 0; i < 8; i++)
                    z[lrow * 68 + lk + i] = (v[i] - mn) * rstd * g2s[0][lk + i] + b2s[0][lk + i];
            } else {
                int row = row0 + lrow;
                int last = (row % SEQ == SEQ - 1);
#pragma unroll
                for (int i = 0; i < 8; i++) {
                    float res = (v[i] - mn) * rstd * g2s[1][lk + i] + b2s[1][lk + i];
                    out[(size_t)row * H + lk + i] = res;
                    if (last)
                        out[(size_t)NROW * H + (row / SEQ) * H + lk + i] = res;
                }
            }
        }
        __syncthreads();

        if (l == 0) {   // re-zero upd for layer 1's atomicAdd accumulation
            for (int idx = tid; idx < 64 * 17; idx += 512)
                *(f32x4*)&upd[idx * 4] = (f32x4){0.f, 0.f, 0.f, 0.f};
            __syncthreads();
        }
    }
}

extern "C" void kernel_launch(void* const* d_in, const int* in_sizes, int n_in,
                              void* d_out, int out_size, void* d_ws, size_t ws_size,
                              hipStream_t stream) {
    const float* x    = (const float*)d_in[0];
    const float* wih0 = (const float*)d_in[1];
    const float* whh0 = (const float*)d_in[2];
    const float* bih0 = (const float*)d_in[3];
    const float* bhh0 = (const float*)d_in[4];
    const float* wih1 = (const float*)d_in[5];
    const float* whh1 = (const float*)d_in[6];
    const float* bih1 = (const float*)d_in[7];
    const float* bhh1 = (const float*)d_in[8];
    const float* coeffs = (const float*)d_in[9];
    const float* ln1g = (const float*)d_in[10];
    const float* ln1b = (const float*)d_in[11];
    const float* w1   = (const float*)d_in[12];
    const float* b1   = (const float*)d_in[13];
    const float* w2   = (const float*)d_in[14];
    const float* b2   = (const float*)d_in[15];
    const float* ln2g = (const float*)d_in[16];
    const float* ln2b = (const float*)d_in[17];

    float* out = (float*)d_out;
    float* ws  = (float*)d_ws;
    float* xpT = ws;                               // 16000*192 = 3,072,000 floats
    float* wtp = ws + (size_t)NROW * GDIM;         // 24,576 floats
    short* bfa = (short*)(wtp + GDIM * DM);        // bf16 fragment area
    float* hbuf = out;                             // reuse first 1,024,000 floats of d_out

    // one fused pack launch: 24576 + 2*(153600+8192+8192) = 364544 = 1424*256
    pack_all<<<1424, 256, 0, stream>>>(wih0, coeffs, w1, w2, wtp, bfa);
    xp0_gemm<<<NROW / 64, 192, 0, stream>>>(x, wtp, bih0, xpT);
    gru_fused<<<BSZ, 768, 0, stream>>>(xpT, whh0, bhh0, wih1, bih1, whh1, bhh1, hbuf);
    sindy_fused<<<NROW / 64, 512, 0, stream>>>(hbuf, bfa, ln1g, ln1b, b1, b2,
                                               ln2g, ln2b, out);
}

// Round 9
// 465.120 us; speedup vs baseline: 1.6629x; 1.0970x over previous
//
#include <hip/hip_runtime.h>
#include <hip/hip_bf16.h>
#include <math.h>

#define H 64
#define DM 128
#define GDIM 192      // 3*H
#define BSZ 32
#define SEQ 500
#define NROW (BSZ*SEQ)  // 16000
#define LIBN 2145
#define FFD 128
#define NKC2 75       // padded grouped-K chunks of 32 (2400 slots, 300 groups)
#define NGRP 300
#define CPK2 153600   // NKC2*4*64*8 shorts per layer

typedef __attribute__((ext_vector_type(8))) short short8;   // bf16x8 MFMA operand
typedef __attribute__((ext_vector_type(4))) float f32x4;    // MFMA accumulator
typedef __attribute__((ext_vector_type(2))) float f32x2;    // packed-math pair
typedef __attribute__((ext_vector_type(4))) unsigned u32x4;

__device__ __forceinline__ float sigf(float x) {
    return 1.0f / (1.0f + __expf(-x));
}
__device__ __forceinline__ float tanhfast(float x) {
    x = fminf(fmaxf(x, -15.0f), 15.0f);
    float t = __expf(-2.0f * x);
    return (1.0f - t) / (1.0f + t);
}
__device__ __forceinline__ short bf16r(float f) {   // fp32 -> bf16 rne
    unsigned u = __float_as_uint(f);
    unsigned r = (u + 0x7fffu + ((u >> 16) & 1u)) >> 16;
    return (short)r;
}
// packed dual-FMA: d.lo = a.lo*b.lo + c.lo, d.hi = a.hi*b.hi + c.hi (1 inst vs 2)
__device__ __forceinline__ f32x2 pkfma(f32x2 a, f32x2 b, f32x2 c) {
    f32x2 d;
    asm("v_pk_fma_f32 %0, %1, %2, %3" : "=v"(d) : "v"(a), "v"(b), "v"(c));
    return d;
}

// decode grouped-K group id -> (a, b): af[j] = z[a] * z[b + j], j = 0..7
__device__ __forceinline__ void grp_decode(int g, int& a, int& b) {
    if (g < 8) { a = 64; b = g * 8; }                 // linear: 1 * z[8g..8g+7]
    else if (g == 8 || g >= 297) { a = 64; b = 64; }  // const slot / padding
    else {
        int G = g - 9, acc = 0;
        a = 0; b = 0;
        for (int i2 = 0; i2 < 64; i2++) {
            int cnt = 8 - (i2 >> 3);                  // aligned 8-groups covering [i2,63]
            if (G < acc + cnt) { a = i2; b = ((i2 >> 3) + (G - acc)) * 8; break; }
            acc += cnt;
        }
    }
}

// ---------------- ONE fused pack kernel -----------------------------------------------
// wih0 section now emits k-major W^T: wt2[k*192+g] = wih0[g*128+k] (for the
// register-tiled xp0_gemm). Rest unchanged.
__global__ void pack_all(const float* __restrict__ wih0,
                         const float* __restrict__ coeffs,
                         const float* __restrict__ w1,
                         const float* __restrict__ w2,
                         float* __restrict__ wtp,
                         short* __restrict__ bfa) {
    int idx = blockIdx.x * 256 + threadIdx.x;        // grid covers exactly 364544
    if (idx < GDIM * DM) {                           // ---- wih0 -> wt2 (k-major) ----
        int k = idx / GDIM;
        int g = idx - k * GDIM;
        wtp[idx] = wih0[g * DM + k];
        return;
    }
    int r = idx - GDIM * DM;
    int l = r / (CPK2 + 2 * 8192);
    int q = r % (CPK2 + 2 * 8192);
    if (q < CPK2) {                                  // ---- coef (grouped-K) ----
        const float* coef = coeffs + (size_t)l * LIBN * H;
        int j = q & 7, lane = (q >> 3) & 63, nt = (q >> 9) & 3, kc = q >> 11;
        int grp = kc * 4 + (lane >> 4);
        int row = -1;
        if (grp < 8) row = 1 + grp * 8 + j;
        else if (grp == 8) row = (j == 0) ? 0 : -1;
        else if (grp < 297) {
            int a, b;
            grp_decode(grp, a, b);
            int jdx = b + j;
            if (jdx >= a) row = 65 + a * 64 - (a * (a - 1)) / 2 + (jdx - a);
        }
        int c = nt * 16 + (lane & 15);
        bfa[(size_t)l * CPK2 + q] = (row >= 0) ? bf16r(coef[(size_t)row * H + c]) : (short)0;
        return;
    }
    int q2 = q - CPK2;
    if (q2 < 8192) {                                 // ---- W1^T fragments ----
        const float* w1l = w1 + (size_t)l * FFD * H;
        int j = q2 & 7, lane = (q2 >> 3) & 63, nt = (q2 >> 9) & 7, kc = q2 >> 12;
        int k = kc * 32 + ((lane >> 4) << 3) + j;
        int n = nt * 16 + (lane & 15);
        bfa[(size_t)2 * CPK2 + l * 8192 + q2] = bf16r(w1l[(size_t)n * H + k]);
        return;
    }
    int q3 = q2 - 8192;                              // ---- W2^T fragments ----
    const float* w2l = w2 + (size_t)l * H * FFD;
    int j = q3 & 7, lane = (q3 >> 3) & 63, nt = (q3 >> 9) & 3, kc = q3 >> 11;
    int k = kc * 32 + ((lane >> 4) << 3) + j;
    int n = nt * 16 + (lane & 15);
    bfa[(size_t)2 * CPK2 + 2 * 8192 + l * 8192 + q3] = bf16r(w2l[(size_t)n * FFD + k]);
}

// ---------------- xp0 = x @ Wih0^T + bih0: register-tiled outer-product --------------
// Old version: per wave 2048 broadcast ds_read_b128 + 8192 dependent FMA (suspected
// hidden ~170µs sink — only untouched kernel in 9 rounds). New: lane (i=lane>>2,
// j=lane&3) owns 4 rows x (3 tiles x 4 cols); per k4: 4 global b128 (x, L1-hot) +
// 12 LDS b128 (W^T broadcast, conflict-free) + 192 FMA -> FMA-bound ~10µs.
// Accumulation order (k ascending, bias-init) identical to old kernel.
__global__ __launch_bounds__(256, 1) void xp0_gemm(const float* __restrict__ x,
                                                   const float* __restrict__ wt2,
                                                   const float* __restrict__ bih0,
                                                   float* __restrict__ xpT) {
    __shared__ __align__(16) float wlds[DM * GDIM];   // 128 x 192 k-major, 96 KB
    int tid = threadIdx.x;
    int wv = __builtin_amdgcn_readfirstlane(tid >> 6);
    int lane = tid & 63;

    for (int p = tid; p < DM * GDIM / 4; p += 256)    // stage W^T: coalesced, one-time
        ((f32x4*)wlds)[p] = ((const f32x4*)wt2)[p];

    int i = lane >> 2;                                // row group 0..15
    int j = lane & 3;                                 // col group 0..3
    int rb = blockIdx.x * 64;
    int row0 = rb + 4 * i;

    f32x4 acc[3][4];
#pragma unroll
    for (int t = 0; t < 3; t++) {
        f32x4 bv = *(const f32x4*)(bih0 + 16 * (wv + 4 * t) + 4 * j);
#pragma unroll
        for (int ii = 0; ii < 4; ii++) acc[t][ii] = bv;
    }
    __syncthreads();

    const float* xr0 = x + (size_t)row0 * DM;
    for (int k4 = 0; k4 < 32; k4++) {
        f32x4 xr[4];
#pragma unroll
        for (int ii = 0; ii < 4; ii++)
            xr[ii] = *(const f32x4*)(xr0 + ii * DM + k4 * 4);
#pragma unroll
        for (int t = 0; t < 3; t++) {
            int cb = 16 * (wv + 4 * t);
#pragma unroll
            for (int e = 0; e < 4; e++) {
                f32x4 wvv = *(const f32x4*)&wlds[(k4 * 4 + e) * GDIM + cb + 4 * j];
#pragma unroll
                for (int ii = 0; ii < 4; ii++)
                    acc[t][ii] += wvv * xr[ii][e];
            }
        }
    }
    // epilogue: rows row0..row0+3 share one xpT chunk (rb,500 both %4==0 -> ss&3==0);
    // store f32x4 over the e (=row-within-chunk) axis.
    int bb = row0 / 500;
    int ss = row0 - bb * 500;
    float* base = xpT + ((size_t)(bb * 125 + (ss >> 2)) * GDIM) * 4;
#pragma unroll
    for (int t = 0; t < 3; t++) {
        int cb = 16 * (wv + 4 * t);
#pragma unroll
        for (int jj = 0; jj < 4; jj++) {
            int g = cb + 4 * j + jj;
            f32x4 v = { acc[t][0][jj], acc[t][1][jj], acc[t][2][jj], acc[t][3][jj] };
            *(f32x4*)(base + (size_t)g * 4) = v;
        }
    }
}

// ---------------- fused 2-layer GRU scan: R7 12-wave + pk_fma (276 µs, FROZEN) -------
__global__ __launch_bounds__(768, 3) void gru_fused(const float* __restrict__ xpT,
                                                    const float* __restrict__ whh0,
                                                    const float* __restrict__ bhh0,
                                                    const float* __restrict__ wih1,
                                                    const float* __restrict__ bih1,
                                                    const float* __restrict__ whh1,
                                                    const float* __restrict__ bhh1,
                                                    float* __restrict__ hbuf) {
    int b = blockIdx.x;
    int tid = threadIdx.x;
    int wv = __builtin_amdgcn_readfirstlane(tid >> 6);
    int lane = tid & 63;
    int m = wv % 3;
    int q = wv / 3;
    int k0 = q * 16;

    __shared__ __align__(16) float h0s[H];
    __shared__ __align__(16) float h1s[H];
    __shared__ float part[3][4][GDIM];

    if (tid < H) { h0s[tid] = 0.0f; h1s[tid] = 0.0f; }

    const float* W = (m == 0) ? whh0 : (m == 1) ? wih1 : whh1;
    f32x2 wrp[8], wzp[8], wnp[8];                  // 48 weight VGPRs as f32x2 pairs
#pragma unroll
    for (int k4 = 0; k4 < 4; k4++) {
        f32x4 a = ((const f32x4*)(W + (size_t)lane * H + k0))[k4];
        f32x4 c = ((const f32x4*)(W + (size_t)(H + lane) * H + k0))[k4];
        f32x4 d = ((const f32x4*)(W + (size_t)(2 * H + lane) * H + k0))[k4];
        wrp[2*k4]   = __builtin_shufflevector(a, a, 0, 1);
        wrp[2*k4+1] = __builtin_shufflevector(a, a, 2, 3);
        wzp[2*k4]   = __builtin_shufflevector(c, c, 0, 1);
        wzp[2*k4+1] = __builtin_shufflevector(c, c, 2, 3);
        wnp[2*k4]   = __builtin_shufflevector(d, d, 0, 1);
        wnp[2*k4+1] = __builtin_shufflevector(d, d, 2, 3);
    }

    float b0r = 0, b0z = 0, b0n = 0;
    float b1ir = 0, b1iz = 0, b1in = 0, b1hr = 0, b1hz = 0, b1hn = 0;
    float hreg0 = 0.0f, hreg1 = 0.0f;
    float hb4[4] = {0.f, 0.f, 0.f, 0.f};
    f32x4 xc[4][3];
    const float* xpB = xpT + (size_t)b * 125 * GDIM * 4;

    if (wv == 0) {
        b0r = bhh0[lane]; b0z = bhh0[H + lane]; b0n = bhh0[2 * H + lane];
#pragma unroll
        for (int g3 = 0; g3 < 3; g3++) {
            xc[0][g3] = *(const f32x4*)(xpB + ((size_t)0 * GDIM + g3 * 64 + lane) * 4);
            xc[1][g3] = *(const f32x4*)(xpB + ((size_t)1 * GDIM + g3 * 64 + lane) * 4);
        }
    } else if (wv == 2) {
        b1ir = bih1[lane]; b1iz = bih1[H + lane]; b1in = bih1[2 * H + lane];
        b1hr = bhh1[lane]; b1hz = bhh1[H + lane]; b1hn = bhh1[2 * H + lane];
    }
    __syncthreads();

    auto loadch = [&](int c, int buf) {
        if (c < 125) {
#pragma unroll
            for (int g3 = 0; g3 < 3; g3++)
                xc[buf][g3] = *(const f32x4*)(xpB + ((size_t)c * GDIM + g3 * 64 + lane) * 4);
        }
    };

    auto step = [&](int s, int e, float xr, float xz, float xn) {
        const float* hv = (m == 2) ? h1s : h0s;
        f32x2 arp = {0.f, 0.f}, azp = {0.f, 0.f}, anp = {0.f, 0.f};
#pragma unroll
        for (int t4 = 0; t4 < 4; t4++) {
            f32x4 h4 = ((const f32x4*)(hv + k0))[t4];
            f32x2 hlo = __builtin_shufflevector(h4, h4, 0, 1);
            f32x2 hhi = __builtin_shufflevector(h4, h4, 2, 3);
            arp = pkfma(wrp[2*t4], hlo, arp);
            arp = pkfma(wrp[2*t4+1], hhi, arp);
            azp = pkfma(wzp[2*t4], hlo, azp);
            azp = pkfma(wzp[2*t4+1], hhi, azp);
            anp = pkfma(wnp[2*t4], hlo, anp);
            anp = pkfma(wnp[2*t4+1], hhi, anp);
        }
        part[m][q][lane] = arp[0] + arp[1];
        part[m][q][H + lane] = azp[0] + azp[1];
        part[m][q][2 * H + lane] = anp[0] + anp[1];
        __syncthreads();

        if (wv == 0) {
            if (s < SEQ) {
                float gr = b0r, gz = b0z, gn = b0n;
#pragma unroll
                for (int qq = 0; qq < 4; qq++) {
                    gr += part[0][qq][lane];
                    gz += part[0][qq][H + lane];
                    gn += part[0][qq][2 * H + lane];
                }
                float rg = sigf(xr + gr);
                float zg = sigf(xz + gz);
                float ng = tanhfast(xn + rg * gn);
                hreg0 = (1.0f - zg) * ng + zg * hreg0;
                h0s[lane] = hreg0;
            }
        } else if (wv == 2) {
            if (s >= 1) {
                float xr1 = b1ir, xz1 = b1iz, xn1 = b1in;
                float gr1 = b1hr, gz1 = b1hz, gn1 = b1hn;
#pragma unroll
                for (int qq = 0; qq < 4; qq++) {
                    xr1 += part[1][qq][lane];
                    xz1 += part[1][qq][H + lane];
                    xn1 += part[1][qq][2 * H + lane];
                    gr1 += part[2][qq][lane];
                    gz1 += part[2][qq][H + lane];
                    gn1 += part[2][qq][2 * H + lane];
                }
                float rg = sigf(xr1 + gr1);
                float zg = sigf(xz1 + gz1);
                float ng = tanhfast(xn1 + rg * gn1);
                hreg1 = (1.0f - zg) * ng + zg * hreg1;
                h1s[lane] = hreg1;
                hb4[(e + 3) & 3] = hreg1;                 // h1[s-1], (s-1)&3 == (e+3)&3
                if (e == 0) {                              // s in {4,8,...,500}: flush h1[s-4..s-1]
                    float* dst = hbuf + ((size_t)b * SEQ + (s - 4)) * H + lane;
#pragma unroll
                    for (int t = 0; t < 4; t++) dst[t * H] = hb4[t];
                }
            }
        }
        __syncthreads();
    };

    for (int scb = 0; scb < 31; scb++) {
#pragma unroll
        for (int sci = 0; sci < 4; sci++) {
            int sc = scb * 4 + sci;
            if (wv == 0 && (sci & 1) == 0) {
                loadch(sc + 2, (sci + 2) & 3);
                loadch(sc + 3, (sci + 3) & 3);
            }
            int s0 = sc * 4;
            step(s0 + 0, 0, xc[sci][0][0], xc[sci][1][0], xc[sci][2][0]);
            step(s0 + 1, 1, xc[sci][0][1], xc[sci][1][1], xc[sci][2][1]);
            step(s0 + 2, 2, xc[sci][0][2], xc[sci][1][2], xc[sci][2][2]);
            step(s0 + 3, 3, xc[sci][0][3], xc[sci][1][3], xc[sci][2][3]);
        }
    }
    {   // sc = 124 (buf 0, loaded at sc=122)
        step(496, 0, xc[0][0][0], xc[0][1][0], xc[0][2][0]);
        step(497, 1, xc[0][0][1], xc[0][1][1], xc[0][2][1]);
        step(498, 2, xc[0][0][2], xc[0][1][2], xc[0][2][2]);
        step(499, 3, xc[0][0][3], xc[0][1][3], xc[0][2][3]);
    }
    // tail s = 500: produces h1[499] and flushes h1[496..499]
    step(500, 0, 0.0f, 0.0f, 0.0f);
}

// ---------------- FUSED 2-layer SINDy kernel + parallel LN (unchanged from R8) -------
__global__ __launch_bounds__(512) void sindy_fused(const float* __restrict__ hbuf_in,
                                                   const short* __restrict__ bfa,
                                                   const float* __restrict__ ln1g,
                                                   const float* __restrict__ ln1b,
                                                   const float* __restrict__ b1g,
                                                   const float* __restrict__ b2g,
                                                   const float* __restrict__ ln2g,
                                                   const float* __restrict__ ln2b,
                                                   float* __restrict__ out) {
    __shared__ float z[65 * 68];                   // row 64 = zero pad (safe b-reads)
    __shared__ float upd[64 * 68];
    __shared__ float ff[64 * 132];
    __shared__ unsigned kmap2[NGRP];
    __shared__ float bfs1[2][FFD], bfs2[2][H];
    __shared__ float g1s[2][H], b1s[2][H], g2s[2][H], b2s[2][H];

    int tid = threadIdx.x;
    int wv = __builtin_amdgcn_readfirstlane(tid >> 6);
    int lane = tid & 63;
    int row0 = blockIdx.x * 64;

    for (int idx = tid; idx < 64 * 16; idx += 512) {
        int r = idx >> 4, c4 = idx & 15;
        *(f32x4*)&z[r * 68 + c4 * 4] = *(const f32x4*)&hbuf_in[(size_t)(row0 + r) * H + c4 * 4];
    }
    for (int idx = tid; idx < 64 * 17; idx += 512)
        *(f32x4*)&upd[idx * 4] = (f32x4){0.f, 0.f, 0.f, 0.f};
    if (tid < 64) {
        z[tid * 68 + 64] = 1.0f; z[tid * 68 + 65] = 0.0f;
        z[tid * 68 + 66] = 0.0f; z[tid * 68 + 67] = 0.0f;
    }
    if (tid < 68) z[64 * 68 + tid] = 0.0f;         // zero pad row
    if (tid < NGRP) {
        int a, b;
        grp_decode(tid, a, b);
        kmap2[tid] = ((unsigned)a << 16) | (unsigned)b;
    }
    if (tid < FFD) { bfs1[0][tid] = b1g[tid]; bfs1[1][tid] = b1g[FFD + tid]; }
    if (tid < H) {
        bfs2[0][tid] = b2g[tid];      bfs2[1][tid] = b2g[H + tid];
        g1s[0][tid] = ln1g[tid];      g1s[1][tid] = ln1g[H + tid];
        b1s[0][tid] = ln1b[tid];      b1s[1][tid] = ln1b[H + tid];
        g2s[0][tid] = ln2g[tid];      g2s[1][tid] = ln2g[H + tid];
        b2s[0][tid] = ln2b[tid];      b2s[1][tid] = ln2b[H + tid];
    }
    __syncthreads();

    int kj0 = ((lane >> 4) << 3);
    int m0 = (wv & 3) * 16;
    int m = m0 + (lane & 15);
    int rbase = m0 + ((lane >> 4) << 2);
    int cb16 = lane & 15;
    const float* zrow = &z[m * 68];
    int lrow = tid >> 3;                           // parallel-LN: row, 8 threads/row
    int lk = (tid & 7) * 8;                        // this thread's 8-col slice

#pragma unroll
    for (int l = 0; l < 2; l++) {
        const short* cpk = bfa + (size_t)l * CPK2;
        const short* w1p = bfa + (size_t)2 * CPK2 + l * 8192;
        const short* w2p = bfa + (size_t)2 * CPK2 + 2 * 8192 + l * 8192;

        // ---- phase 1: upd = theta @ coef (grouped-K, k-split 2-way) ----
        {
            int p = wv >> 2;
            f32x4 acc[4] = {{0,0,0,0},{0,0,0,0},{0,0,0,0},{0,0,0,0}};
            for (int kc = p; kc < NKC2; kc += 2) {
                unsigned ab = kmap2[kc * 4 + (lane >> 4)];
                float za = zrow[ab >> 16];
                const float* zb = &zrow[ab & 0xffffu];
                f32x4 z0 = *(const f32x4*)zb;
                f32x4 z1 = *(const f32x4*)(zb + 4);
                short8 af;
                af[0] = bf16r(za * z0[0]);
                af[1] = bf16r(za * z0[1]);
                af[2] = bf16r(za * z0[2]);
                af[3] = bf16r(za * z0[3]);
                af[4] = bf16r(za * z1[0]);
                af[5] = bf16r(za * z1[1]);
                af[6] = bf16r(za * z1[2]);
                af[7] = bf16r(za * z1[3]);
                const short* cb = cpk + ((size_t)(kc * 4) * 64 + lane) * 8;
#pragma unroll
                for (int nt = 0; nt < 4; nt++) {
                    short8 bf = *(const short8*)(cb + (size_t)nt * 512);
                    acc[nt] = __builtin_amdgcn_mfma_f32_16x16x32_bf16(af, bf, acc[nt], 0, 0, 0);
                }
            }
#pragma unroll
            for (int nt = 0; nt < 4; nt++)
#pragma unroll
                for (int r = 0; r < 4; r++)
                    atomicAdd(&upd[(rbase + r) * 68 + nt * 16 + cb16], acc[nt][r]);
        }
        __syncthreads();

        // ---- LN1 (all 512 threads, 8/row) -> z ----
        {
            float v[8];
            float s1 = 0.0f;
#pragma unroll
            for (int i = 0; i < 8; i++) {
                v[i] = z[lrow * 68 + lk + i] + upd[lrow * 68 + lk + i];
                s1 += v[i];
            }
            s1 += __shfl_xor(s1, 1); s1 += __shfl_xor(s1, 2); s1 += __shfl_xor(s1, 4);
            float mn = s1 * (1.0f / 64.0f);
            float s2 = 0.0f;
#pragma unroll
            for (int i = 0; i < 8; i++) { float d = v[i] - mn; s2 += d * d; }
            s2 += __shfl_xor(s2, 1); s2 += __shfl_xor(s2, 2); s2 += __shfl_xor(s2, 4);
            float rstd = 1.0f / sqrtf(s2 * (1.0f / 64.0f) + 1e-5f);
#pragma unroll
            for (int i = 0; i < 8; i++)
                z[lrow * 68 + lk + i] = (v[i] - mn) * rstd * g1s[l][lk + i] + b1s[l][lk + i];
        }
        __syncthreads();

        // ---- phase 3: ff = gelu(LN1 @ W1^T + b1) ----
        {
            int nq = wv >> 2;
            f32x4 acc[4] = {{0,0,0,0},{0,0,0,0},{0,0,0,0},{0,0,0,0}};
#pragma unroll
            for (int kc = 0; kc < 2; kc++) {
                f32x4 za = *(const f32x4*)&z[m * 68 + kc * 32 + kj0];
                f32x4 zb = *(const f32x4*)&z[m * 68 + kc * 32 + kj0 + 4];
                short8 af;
                af[0] = bf16r(za[0]); af[1] = bf16r(za[1]); af[2] = bf16r(za[2]); af[3] = bf16r(za[3]);
                af[4] = bf16r(zb[0]); af[5] = bf16r(zb[1]); af[6] = bf16r(zb[2]); af[7] = bf16r(zb[3]);
#pragma unroll
                for (int t = 0; t < 4; t++) {
                    int nt = nq * 4 + t;
                    short8 bf = *(const short8*)(w1p + ((size_t)(kc * 8 + nt) * 64 + lane) * 8);
                    acc[t] = __builtin_amdgcn_mfma_f32_16x16x32_bf16(af, bf, acc[t], 0, 0, 0);
                }
            }
#pragma unroll
            for (int t = 0; t < 4; t++) {
                int col = (nq * 4 + t) * 16 + cb16;
#pragma unroll
                for (int r = 0; r < 4; r++) {
                    float v = acc[t][r] + bfs1[l][col];
                    ff[(rbase + r) * 132 + col] = 0.5f * v * (1.0f + erff(v * 0.70710678118654752f));
                }
            }
        }
        __syncthreads();

        // ---- phase 5: upd = ff @ W2^T + b2 (plain stores, full overwrite) ----
        {
            int nh = wv >> 2;
            f32x4 acc[2] = {{0,0,0,0},{0,0,0,0}};
            const float* frow = &ff[m * 132];
#pragma unroll
            for (int kc = 0; kc < 4; kc++) {
                f32x4 fa = *(const f32x4*)&frow[kc * 32 + kj0];
                f32x4 fb = *(const f32x4*)&frow[kc * 32 + kj0 + 4];
                short8 af;
                af[0] = bf16r(fa[0]); af[1] = bf16r(fa[1]); af[2] = bf16r(fa[2]); af[3] = bf16r(fa[3]);
                af[4] = bf16r(fb[0]); af[5] = bf16r(fb[1]); af[6] = bf16r(fb[2]); af[7] = bf16r(fb[3]);
#pragma unroll
                for (int t = 0; t < 2; t++) {
                    int nt = nh * 2 + t;
                    short8 bf = *(const short8*)(w2p + ((size_t)(kc * 4 + nt) * 64 + lane) * 8);
                    acc[t] = __builtin_amdgcn_mfma_f32_16x16x32_bf16(af, bf, acc[t], 0, 0, 0);
                }
            }
#pragma unroll
            for (int t = 0; t < 2; t++) {
                int col = (nh * 2 + t) * 16 + cb16;
#pragma unroll
                for (int r = 0; r < 4; r++)
                    upd[(rbase + r) * 68 + col] = acc[t][r] + bfs2[l][col];
            }
        }
        __syncthreads();

        // ---- LN2 (all 512 threads): l=0 -> z (stay in LDS); l=1 -> out ----
        {
            float v[8];
            float s1 = 0.0f;
#pragma unroll
            for (int i = 0; i < 8; i++) {
                v[i] = z[lrow * 68 + lk + i] + upd[lrow * 68 + lk + i];
                s1 += v[i];
            }
            s1 += __shfl_xor(s1, 1); s1 += __shfl_xor(s1, 2); s1 += __shfl_xor(s1, 4);
            float mn = s1 * (1.0f / 64.0f);
            float s2 = 0.0f;
#pragma unroll
            for (int i = 0; i < 8; i++) { float d = v[i] - mn; s2 += d * d; }
            s2 += __shfl_xor(s2, 1); s2 += __shfl_xor(s2, 2); s2 += __shfl_xor(s2, 4);
            float rstd = 1.0f / sqrtf(s2 * (1.0f / 64.0f) + 1e-5f);
            if (l == 0) {
#pragma unroll
                for (int i = 0; i < 8; i++)
                    z[lrow * 68 + lk + i] = (v[i] - mn) * rstd * g2s[0][lk + i] + b2s[0][lk + i];
            } else {
                int row = row0 + lrow;
                int last = (row % SEQ == SEQ - 1);
#pragma unroll
                for (int i = 0; i < 8; i++) {
                    float res = (v[i] - mn) * rstd * g2s[1][lk + i] + b2s[1][lk + i];
                    out[(size_t)row * H + lk + i] = res;
                    if (last)
                        out[(size_t)NROW * H + (row / SEQ) * H + lk + i] = res;
                }
            }
        }
        __syncthreads();

        if (l == 0) {   // re-zero upd for layer 1's atomicAdd accumulation
            for (int idx = tid; idx < 64 * 17; idx += 512)
                *(f32x4*)&upd[idx * 4] = (f32x4){0.f, 0.f, 0.f, 0.f};
            __syncthreads();
        }
    }
}

extern "C" void kernel_launch(void* const* d_in, const int* in_sizes, int n_in,
                              void* d_out, int out_size, void* d_ws, size_t ws_size,
                              hipStream_t stream) {
    const float* x    = (const float*)d_in[0];
    const float* wih0 = (const float*)d_in[1];
    const float* whh0 = (const float*)d_in[2];
    const float* bih0 = (const float*)d_in[3];
    const float* bhh0 = (const float*)d_in[4];
    const float* wih1 = (const float*)d_in[5];
    const float* whh1 = (const float*)d_in[6];
    const float* bih1 = (const float*)d_in[7];
    const float* bhh1 = (const float*)d_in[8];
    const float* coeffs = (const float*)d_in[9];
    const float* ln1g = (const float*)d_in[10];
    const float* ln1b = (const float*)d_in[11];
    const float* w1   = (const float*)d_in[12];
    const float* b1   = (const float*)d_in[13];
    const float* w2   = (const float*)d_in[14];
    const float* b2   = (const float*)d_in[15];
    const float* ln2g = (const float*)d_in[16];
    const float* ln2b = (const float*)d_in[17];

    float* out = (float*)d_out;
    float* ws  = (float*)d_ws;
    float* xpT = ws;                               // 16000*192 = 3,072,000 floats
    float* wtp = ws + (size_t)NROW * GDIM;         // 24,576 floats (k-major W^T)
    short* bfa = (short*)(wtp + GDIM * DM);        // bf16 fragment area
    float* hbuf = out;                             // reuse first 1,024,000 floats of d_out

    // one fused pack launch: 24576 + 2*(153600+8192+8192) = 364544 = 1424*256
    pack_all<<<1424, 256, 0, stream>>>(wih0, coeffs, w1, w2, wtp, bfa);
    xp0_gemm<<<NROW / 64, 256, 0, stream>>>(x, wtp, bih0, xpT);
    gru_fused<<<BSZ, 768, 0, stream>>>(xpT, whh0, bhh0, wih1, bih1, whh1, bhh1, hbuf);
    sindy_fused<<<NROW / 64, 512, 0, stream>>>(hbuf, bfa, ln1g, ln1b, b1, b2,
                                               ln2g, ln2b, out);
}